// Round 2
// baseline (2282.069 us; speedup 1.0000x reference)
//
#include <hip/hip_runtime.h>
#include <math.h>

constexpr int B = 4, S = 2048, D = 1024, H = 16, HD = 64;
constexpr int M = B * S;               // 8192 rows
constexpr float NEGF = -65504.0f;      // fp16 min, matches reference mask fill

// ---------------------------------------------------------------------------
// Kernel 1: fused QKV projection.  y = x @ W^T + b for Wq,Wk,Wv.
// Output written directly in [B,H,S,HD] layout.
// grid (M/64, D/64), block 256. BN=64 == HD so blockIdx.y == head index.
// ---------------------------------------------------------------------------
__global__ __launch_bounds__(256)
void qkv_gemm(const float* __restrict__ x,
              const float* __restrict__ Wq, const float* __restrict__ bq,
              const float* __restrict__ Wk, const float* __restrict__ bk,
              const float* __restrict__ Wv, const float* __restrict__ bv,
              float* __restrict__ qo, float* __restrict__ ko, float* __restrict__ vo)
{
    constexpr int BK = 16, PAD = 68;
    __shared__ float As[BK][PAD];       // x tile, transposed [k][m]
    __shared__ float Bs[3][BK][PAD];    // Wq/Wk/Wv tiles, transposed [k][n]

    const int t  = threadIdx.x;
    const int tx = t & 15, ty = t >> 4;
    const int m0 = blockIdx.x * 64, n0 = blockIdx.y * 64;
    const int lr = t >> 2;             // 0..63  (tile row)
    const int lc = (t & 3) * 4;        // 0,4,8,12 (k-col of float4)

    float acc[3][4][4] = {};

    for (int k0 = 0; k0 < D; k0 += BK) {
        float4 ax = *(const float4*)(x  + (size_t)(m0 + lr) * D + k0 + lc);
        float4 wq = *(const float4*)(Wq + (size_t)(n0 + lr) * D + k0 + lc);
        float4 wk = *(const float4*)(Wk + (size_t)(n0 + lr) * D + k0 + lc);
        float4 wv = *(const float4*)(Wv + (size_t)(n0 + lr) * D + k0 + lc);
        __syncthreads();
        As[lc+0][lr] = ax.x; As[lc+1][lr] = ax.y; As[lc+2][lr] = ax.z; As[lc+3][lr] = ax.w;
        Bs[0][lc+0][lr] = wq.x; Bs[0][lc+1][lr] = wq.y; Bs[0][lc+2][lr] = wq.z; Bs[0][lc+3][lr] = wq.w;
        Bs[1][lc+0][lr] = wk.x; Bs[1][lc+1][lr] = wk.y; Bs[1][lc+2][lr] = wk.z; Bs[1][lc+3][lr] = wk.w;
        Bs[2][lc+0][lr] = wv.x; Bs[2][lc+1][lr] = wv.y; Bs[2][lc+2][lr] = wv.z; Bs[2][lc+3][lr] = wv.w;
        __syncthreads();
#pragma unroll
        for (int kk = 0; kk < BK; ++kk) {
            alignas(16) float a[4], b0[4], b1[4], b2[4];
            *(float4*)a  = *(const float4*)&As[kk][ty * 4];
            *(float4*)b0 = *(const float4*)&Bs[0][kk][tx * 4];
            *(float4*)b1 = *(const float4*)&Bs[1][kk][tx * 4];
            *(float4*)b2 = *(const float4*)&Bs[2][kk][tx * 4];
#pragma unroll
            for (int i = 0; i < 4; ++i)
#pragma unroll
                for (int j = 0; j < 4; ++j) {
                    acc[0][i][j] += a[i] * b0[j];
                    acc[1][i][j] += a[i] * b1[j];
                    acc[2][i][j] += a[i] * b2[j];
                }
        }
    }

    const int hh = blockIdx.y;  // head index (BN == HD)
    const float4 bq4 = *(const float4*)(bq + n0 + tx * 4);
    const float4 bk4 = *(const float4*)(bk + n0 + tx * 4);
    const float4 bv4 = *(const float4*)(bv + n0 + tx * 4);
#pragma unroll
    for (int i = 0; i < 4; ++i) {
        const int m  = m0 + ty * 4 + i;
        const int bb = m >> 11;          // m / S
        const int ss = m & (S - 1);
        const size_t base = (((size_t)bb * H + hh) * S + ss) * HD + tx * 4;
        float4 oq, ok, ov;
        oq.x = acc[0][i][0] + bq4.x; oq.y = acc[0][i][1] + bq4.y;
        oq.z = acc[0][i][2] + bq4.z; oq.w = acc[0][i][3] + bq4.w;
        ok.x = acc[1][i][0] + bk4.x; ok.y = acc[1][i][1] + bk4.y;
        ok.z = acc[1][i][2] + bk4.z; ok.w = acc[1][i][3] + bk4.w;
        ov.x = acc[2][i][0] + bv4.x; ov.y = acc[2][i][1] + bv4.y;
        ov.z = acc[2][i][2] + bv4.z; ov.w = acc[2][i][3] + bv4.w;
        *(float4*)(qo + base) = oq;
        *(float4*)(ko + base) = ok;
        *(float4*)(vo + base) = ov;
    }
}

// ---------------------------------------------------------------------------
// Kernel 2: fp32 flash attention. One block = one (b,h) and 64 q-rows.
// K/V tiles of 32 rows. Online softmax; mask (int32) read straight from
// global (L2-resident per block).
// Thread (tx,ty): q-rows ty+16i (i<4), k-cols tx+16j (j<2), v-cols tx+16j (j<4).
// grid (S/64, B*H), block 256.
// ---------------------------------------------------------------------------
__global__ __launch_bounds__(256)
void attn_kernel(const float* __restrict__ q, const float* __restrict__ k,
                 const float* __restrict__ v, const int* __restrict__ mask,
                 float* __restrict__ ho)
{
    constexpr int PAD = 68, KT = 32, PPAD = 36;
    __shared__ float Qs[64][PAD];
    __shared__ float Ks[KT][PAD];
    __shared__ float Vs[KT][PAD];
    __shared__ float Ps[64][PPAD];

    const int t  = threadIdx.x;
    const int tx = t & 15, ty = t >> 4;
    const int q0 = blockIdx.x * 64;
    const int bh = blockIdx.y;
    const int bb = bh >> 4, hh = bh & 15;
    const float* qb = q + (size_t)bh * S * HD;
    const float* kb = k + (size_t)bh * S * HD;
    const float* vb = v + (size_t)bh * S * HD;
    const int* mb = mask + (size_t)bb * S * S + (size_t)q0 * S;

    // load Q tile, pre-scaled by 1/sqrt(HD)
#pragma unroll
    for (int i = 0; i < 4; ++i) {
        const int f = i * 256 + t;           // float4 index in 64x64 tile
        const int r = f >> 4, c = (f & 15) * 4;
        float4 d4 = *(const float4*)(qb + (size_t)(q0 + r) * HD + c);
        Qs[r][c]     = d4.x * 0.125f;
        Qs[r][c + 1] = d4.y * 0.125f;
        Qs[r][c + 2] = d4.z * 0.125f;
        Qs[r][c + 3] = d4.w * 0.125f;
    }

    float mi[4], li[4], oa[4][4];
#pragma unroll
    for (int i = 0; i < 4; ++i) {
        mi[i] = -INFINITY; li[i] = 0.f;
#pragma unroll
        for (int j = 0; j < 4; ++j) oa[i][j] = 0.f;
    }

    for (int kt = 0; kt < S; kt += KT) {
        __syncthreads();   // previous tile fully consumed
#pragma unroll
        for (int i = 0; i < 2; ++i) {        // stage K,V (32x64 each)
            const int f = i * 256 + t;
            const int r = f >> 4, c = (f & 15) * 4;
            float4 kd = *(const float4*)(kb + (size_t)(kt + r) * HD + c);
            float4 vd = *(const float4*)(vb + (size_t)(kt + r) * HD + c);
            Ks[r][c] = kd.x; Ks[r][c+1] = kd.y; Ks[r][c+2] = kd.z; Ks[r][c+3] = kd.w;
            Vs[r][c] = vd.x; Vs[r][c+1] = vd.y; Vs[r][c+2] = vd.z; Vs[r][c+3] = vd.w;
        }
        __syncthreads();

        // scores: s[i][j] = (q/8) . k
        float sc[4][2] = {};
#pragma unroll
        for (int d0 = 0; d0 < HD; d0 += 4) {
            alignas(16) float qf[4][4], kf[2][4];
#pragma unroll
            for (int i = 0; i < 4; ++i) *(float4*)qf[i] = *(const float4*)&Qs[ty + 16*i][d0];
#pragma unroll
            for (int j = 0; j < 2; ++j) *(float4*)kf[j] = *(const float4*)&Ks[tx + 16*j][d0];
#pragma unroll
            for (int i = 0; i < 4; ++i)
#pragma unroll
                for (int j = 0; j < 2; ++j)
#pragma unroll
                    for (int d = 0; d < 4; ++d)
                        sc[i][j] += qf[i][d] * kf[j][d];
        }
        // mask (int32; nonzero = keep)
#pragma unroll
        for (int i = 0; i < 4; ++i)
#pragma unroll
            for (int j = 0; j < 2; ++j)
                if (!mb[(size_t)(ty + 16*i) * S + kt + tx + 16*j]) sc[i][j] = NEGF;

        // online softmax per q-row (row spread over 16 contiguous lanes)
#pragma unroll
        for (int i = 0; i < 4; ++i) {
            float tm = fmaxf(sc[i][0], sc[i][1]);
#pragma unroll
            for (int off = 1; off < 16; off <<= 1) tm = fmaxf(tm, __shfl_xor(tm, off));
            const float mn    = fmaxf(mi[i], tm);
            const float scale = __expf(mi[i] - mn);
            const float p0 = __expf(sc[i][0] - mn);
            const float p1 = __expf(sc[i][1] - mn);
            float rs = p0 + p1;
#pragma unroll
            for (int off = 1; off < 16; off <<= 1) rs += __shfl_xor(rs, off);
            li[i] = li[i] * scale + rs;
            mi[i] = mn;
#pragma unroll
            for (int j = 0; j < 4; ++j) oa[i][j] *= scale;
            Ps[ty + 16*i][tx]      = p0;
            Ps[ty + 16*i][tx + 16] = p1;
        }
        __syncthreads();

        // PV: oa[i][j] += sum_k Ps[row_i][k] * Vs[k][tx+16j]
#pragma unroll
        for (int k0 = 0; k0 < KT; k0 += 4) {
            alignas(16) float pf[4][4];
#pragma unroll
            for (int i = 0; i < 4; ++i) *(float4*)pf[i] = *(const float4*)&Ps[ty + 16*i][k0];
#pragma unroll
            for (int kk = 0; kk < 4; ++kk) {
                float vv[4];
#pragma unroll
                for (int j = 0; j < 4; ++j) vv[j] = Vs[k0 + kk][tx + 16*j];
#pragma unroll
                for (int i = 0; i < 4; ++i)
#pragma unroll
                    for (int j = 0; j < 4; ++j)
                        oa[i][j] += pf[i][kk] * vv[j];
            }
        }
    }

    // epilogue: normalize and store context in [B,S,D] (D = h*HD+hd)
#pragma unroll
    for (int i = 0; i < 4; ++i) {
        const float inv = 1.0f / li[i];
        const int ss = q0 + ty + 16*i;
        float* dst = ho + ((size_t)bb * S + ss) * D + hh * HD;
        dst[tx]      = oa[i][0] * inv;
        dst[tx + 16] = oa[i][1] * inv;
        dst[tx + 32] = oa[i][2] * inv;
        dst[tx + 48] = oa[i][3] * inv;
    }
}

// ---------------------------------------------------------------------------
// Kernel 3: output projection.  out = hctx @ Wf^T + bf
// grid (M/64, D/64), block 256.
// ---------------------------------------------------------------------------
__global__ __launch_bounds__(256)
void proj_gemm(const float* __restrict__ hin, const float* __restrict__ Wf,
               const float* __restrict__ bf, float* __restrict__ out)
{
    constexpr int BK = 32, PAD = 68;
    __shared__ float As[BK][PAD];
    __shared__ float Bs[BK][PAD];

    const int t  = threadIdx.x;
    const int tx = t & 15, ty = t >> 4;
    const int m0 = blockIdx.x * 64, n0 = blockIdx.y * 64;

    float acc[4][4] = {};

    for (int k0 = 0; k0 < D; k0 += BK) {
        // stage 64x32 tiles: 512 float4, 2 per thread
        float4 av[2], bv[2];
#pragma unroll
        for (int i = 0; i < 2; ++i) {
            const int f = i * 256 + t;
            const int r = f >> 3, c = (f & 7) * 4;   // 8 float4 per row
            av[i] = *(const float4*)(hin + (size_t)(m0 + r) * D + k0 + c);
            bv[i] = *(const float4*)(Wf  + (size_t)(n0 + r) * D + k0 + c);
        }
        __syncthreads();
#pragma unroll
        for (int i = 0; i < 2; ++i) {
            const int f = i * 256 + t;
            const int r = f >> 3, c = (f & 7) * 4;
            As[c][r] = av[i].x; As[c+1][r] = av[i].y; As[c+2][r] = av[i].z; As[c+3][r] = av[i].w;
            Bs[c][r] = bv[i].x; Bs[c+1][r] = bv[i].y; Bs[c+2][r] = bv[i].z; Bs[c+3][r] = bv[i].w;
        }
        __syncthreads();
#pragma unroll
        for (int kk = 0; kk < BK; ++kk) {
            alignas(16) float a[4], b[4];
            *(float4*)a = *(const float4*)&As[kk][ty * 4];
            *(float4*)b = *(const float4*)&Bs[kk][tx * 4];
#pragma unroll
            for (int i = 0; i < 4; ++i)
#pragma unroll
                for (int j = 0; j < 4; ++j)
                    acc[i][j] += a[i] * b[j];
        }
    }

    const float4 bf4 = *(const float4*)(bf + n0 + tx * 4);
#pragma unroll
    for (int i = 0; i < 4; ++i) {
        const int m = m0 + ty * 4 + i;
        float4 o;
        o.x = acc[i][0] + bf4.x; o.y = acc[i][1] + bf4.y;
        o.z = acc[i][2] + bf4.z; o.w = acc[i][3] + bf4.w;
        *(float4*)(out + (size_t)m * D + n0 + tx * 4) = o;
    }
}

// ---------------------------------------------------------------------------
extern "C" void kernel_launch(void* const* d_in, const int* in_sizes, int n_in,
                              void* d_out, int out_size, void* d_ws, size_t ws_size,
                              hipStream_t stream)
{
    const float* x  = (const float*)d_in[0];
    const int* mask = (const int*)d_in[1];
    const float* Wq = (const float*)d_in[2];
    const float* bq = (const float*)d_in[3];
    const float* Wk = (const float*)d_in[4];
    const float* bk = (const float*)d_in[5];
    const float* Wv = (const float*)d_in[6];
    const float* bv = (const float*)d_in[7];
    const float* Wf = (const float*)d_in[8];
    const float* bf = (const float*)d_in[9];
    float* out = (float*)d_out;

    float* q  = (float*)d_ws;                 // [B,H,S,HD]
    float* k  = q  + (size_t)M * D;
    float* v  = k  + (size_t)M * D;
    float* hc = v  + (size_t)M * D;           // [B,S,D] context

    qkv_gemm<<<dim3(M / 64, D / 64), 256, 0, stream>>>(x, Wq, bq, Wk, bk, Wv, bv, q, k, v);
    attn_kernel<<<dim3(S / 64, B * H), 256, 0, stream>>>(q, k, v, mask, hc);
    proj_gemm<<<dim3(M / 64, D / 64), 256, 0, stream>>>(hc, Wf, bf, out);
}

// Round 3
// 412.444 us; speedup vs baseline: 5.5330x; 5.5330x over previous
//
#include <hip/hip_runtime.h>
#include <math.h>

constexpr int S = 2048, D = 1024, H = 16;

typedef __attribute__((ext_vector_type(8))) short bf16x8;
typedef __attribute__((ext_vector_type(4))) short s16x4;
typedef __attribute__((ext_vector_type(4))) float f32x4;

#define MFMA(a, b, c) __builtin_amdgcn_mfma_f32_16x16x32_bf16(a, b, c, 0, 0, 0)

__device__ inline short f2bf(float f) {
    union { float f; unsigned u; } c; c.f = f;
    unsigned u = c.u + 0x7fffu + ((c.u >> 16) & 1u);
    return (short)(u >> 16);
}

// ---------------------------------------------------------------------------
// Convert x and the 4 weight matrices to bf16 (RNE). 3,145,728 float4 groups.
// ---------------------------------------------------------------------------
__global__ __launch_bounds__(256)
void conv_pack(const float* __restrict__ x,  const float* __restrict__ wq,
               const float* __restrict__ wk, const float* __restrict__ wv,
               const float* __restrict__ wf,
               short* __restrict__ xb,  short* __restrict__ wqb,
               short* __restrict__ wkb, short* __restrict__ wvb,
               short* __restrict__ wfb)
{
    int i = blockIdx.x * 256 + threadIdx.x;
    const float* s; short* d; int o;
    if (i < 2097152) { s = x; d = xb; o = i; }
    else {
        int j = i - 2097152; int wsel = j >> 18; o = j & 262143;
        s = wsel == 0 ? wq : wsel == 1 ? wk : wsel == 2 ? wv : wf;
        d = wsel == 0 ? wqb : wsel == 1 ? wkb : wsel == 2 ? wvb : wfb;
    }
    float4 v = ((const float4*)s)[o];
    s16x4 r; r.x = f2bf(v.x); r.y = f2bf(v.y); r.z = f2bf(v.z); r.w = f2bf(v.w);
    ((s16x4*)d)[o] = r;
}

// mask int32 -> u8 (1 = keep). 4,194,304 int4 groups.
__global__ __launch_bounds__(256)
void conv_mask(const int* __restrict__ m, unsigned char* __restrict__ o)
{
    int i = blockIdx.x * 256 + threadIdx.x;
    int4 v = ((const int4*)m)[i];
    unsigned r = (v.x != 0 ? 1u : 0u) | (v.y != 0 ? 1u : 0u) << 8 |
                 (v.z != 0 ? 1u : 0u) << 16 | (v.w != 0 ? 1u : 0u) << 24;
    ((unsigned*)o)[i] = r;
}

// ---------------------------------------------------------------------------
// Fused QKV GEMM, bf16 MFMA.  y = x @ W^T + b for Wq,Wk,Wv.
// grid (128, 16) = (M/64, D/64); block 256 = 4 waves; wave w owns rows w*16..+15.
// q output pre-scaled by 1/8. Outputs bf16 in [B,H,S,HD].
// ---------------------------------------------------------------------------
__global__ __launch_bounds__(256, 2)
void qkv_mfma(const short* __restrict__ xb,
              const short* __restrict__ wqb, const short* __restrict__ wkb,
              const short* __restrict__ wvb,
              const float* __restrict__ bq, const float* __restrict__ bk,
              const float* __restrict__ bv,
              short* __restrict__ qo, short* __restrict__ ko, short* __restrict__ vo)
{
    __shared__ short As[64 * 72];
    __shared__ short Bs[3][64 * 72];
    const int t = threadIdx.x;
    const int lane = t & 63, w = t >> 6;
    const int lr = lane & 15, lg = lane >> 4;
    const int m0 = blockIdx.x * 64;
    const int hh = blockIdx.y;
    const int n0 = hh * 64;
    const int srow = t >> 2, sc0 = (t & 3) * 16;

    f32x4 z = {0.f, 0.f, 0.f, 0.f};
    f32x4 acc[3][4];
#pragma unroll
    for (int m = 0; m < 3; ++m)
#pragma unroll
        for (int n = 0; n < 4; ++n) acc[m][n] = z;

    for (int kt = 0; kt < D; kt += 64) {
        const short* xp = xb + (m0 + srow) * D + kt + sc0;
        const short* qp = wqb + (n0 + srow) * D + kt + sc0;
        const short* kp = wkb + (n0 + srow) * D + kt + sc0;
        const short* vp = wvb + (n0 + srow) * D + kt + sc0;
        int4 a0 = *(const int4*)(xp),     a1 = *(const int4*)(xp + 8);
        int4 q0v = *(const int4*)(qp),    q1v = *(const int4*)(qp + 8);
        int4 k0v = *(const int4*)(kp),    k1v = *(const int4*)(kp + 8);
        int4 v0v = *(const int4*)(vp),    v1v = *(const int4*)(vp + 8);
        __syncthreads();
        *(int4*)&As[srow * 72 + sc0] = a0;     *(int4*)&As[srow * 72 + sc0 + 8] = a1;
        *(int4*)&Bs[0][srow * 72 + sc0] = q0v; *(int4*)&Bs[0][srow * 72 + sc0 + 8] = q1v;
        *(int4*)&Bs[1][srow * 72 + sc0] = k0v; *(int4*)&Bs[1][srow * 72 + sc0 + 8] = k1v;
        *(int4*)&Bs[2][srow * 72 + sc0] = v0v; *(int4*)&Bs[2][srow * 72 + sc0 + 8] = v1v;
        __syncthreads();
#pragma unroll
        for (int ks = 0; ks < 2; ++ks) {
            bf16x8 af = *(const bf16x8*)&As[(w * 16 + lr) * 72 + ks * 32 + lg * 8];
#pragma unroll
            for (int n = 0; n < 4; ++n) {
                bf16x8 b0 = *(const bf16x8*)&Bs[0][(n * 16 + lr) * 72 + ks * 32 + lg * 8];
                acc[0][n] = MFMA(af, b0, acc[0][n]);
                bf16x8 b1 = *(const bf16x8*)&Bs[1][(n * 16 + lr) * 72 + ks * 32 + lg * 8];
                acc[1][n] = MFMA(af, b1, acc[1][n]);
                bf16x8 b2 = *(const bf16x8*)&Bs[2][(n * 16 + lr) * 72 + ks * 32 + lg * 8];
                acc[2][n] = MFMA(af, b2, acc[2][n]);
            }
        }
    }

    const float* biases[3] = {bq, bk, bv};
    short* outs[3] = {qo, ko, vo};
#pragma unroll
    for (int mat = 0; mat < 3; ++mat) {
#pragma unroll
        for (int n = 0; n < 4; ++n) {
            float bi = biases[mat][n0 + n * 16 + lr];
#pragma unroll
            for (int r = 0; r < 4; ++r) {
                int m = m0 + w * 16 + lg * 4 + r;
                int bb = m >> 11, ss = m & (S - 1);
                float val = acc[mat][n][r] + bi;
                if (mat == 0) val *= 0.125f;   // q pre-scaled by 1/sqrt(HD)
                outs[mat][(((size_t)bb * H + hh) * S + ss) * 64 + n * 16 + lr] = f2bf(val);
            }
        }
    }
}

// ---------------------------------------------------------------------------
// Flash attention, bf16 MFMA. grid (32, 64) = (S/64, B*H); block 256 = 4 waves.
// Wave w owns q-rows w*16..+15 of the 64-row Q tile. K-tile = 64 keys.
// K staged with permuted rows (LDS row 16(k&3)+(k>>2)) so each lane's 4 scores
// are consecutive keys 4*lr..+3 -> mask = 1 u32 read, P-write = 1 b64 per row.
// V staged transposed (Vt[d][k]). Online softmax; mask applied as p *= m.
// ---------------------------------------------------------------------------
__global__ __launch_bounds__(256, 2)
void attn_mfma(const short* __restrict__ qg, const short* __restrict__ kg,
               const short* __restrict__ vg, const unsigned char* __restrict__ mu,
               short* __restrict__ hc)
{
    __shared__ short Qs[64 * 72];
    __shared__ short Ks[64 * 72];
    __shared__ short Vt[64 * 72];
    __shared__ short Pw[4][16 * 72];
    __shared__ unsigned char Ms[64 * 80];

    const int t = threadIdx.x, lane = t & 63, w = t >> 6;
    const int lr = lane & 15, lg = lane >> 4;
    const int q0 = blockIdx.x * 64;
    const int bh = blockIdx.y, bb = bh >> 4, hh = bh & 15;
    const short* qb = qg + (size_t)bh * S * 64;
    const short* kb = kg + (size_t)bh * S * 64;
    const short* vb = vg + (size_t)bh * S * 64;
    const unsigned char* mb = mu + (size_t)bb * S * S + (size_t)q0 * S;

    const int srow = t >> 2, sc0 = (t & 3) * 16;
    {
        const short* qp = qb + (q0 + srow) * 64 + sc0;
        int4 a0 = *(const int4*)(qp), a1 = *(const int4*)(qp + 8);
        *(int4*)&Qs[srow * 72 + sc0] = a0;
        *(int4*)&Qs[srow * 72 + sc0 + 8] = a1;
    }
    __syncthreads();
    bf16x8 qf[2];
    qf[0] = *(const bf16x8*)&Qs[(w * 16 + lr) * 72 + lg * 8];
    qf[1] = *(const bf16x8*)&Qs[(w * 16 + lr) * 72 + 32 + lg * 8];

    f32x4 z = {0.f, 0.f, 0.f, 0.f};
    float mi[4], li[4];
    f32x4 oacc[4];
#pragma unroll
    for (int r = 0; r < 4; ++r) { mi[r] = -INFINITY; li[r] = 0.f; }
#pragma unroll
    for (int n = 0; n < 4; ++n) oacc[n] = z;

    const int vrow = (t >> 3) * 2, vd0 = (t & 7) * 8;      // V transpose staging
    const int krloc = 16 * (srow & 3) + (srow >> 2);       // permuted K row

    for (int kt = 0; kt < S; kt += 64) {
        const short* kp = kb + (kt + srow) * 64 + sc0;
        int4 k0v = *(const int4*)(kp), k1v = *(const int4*)(kp + 8);
        int4 va  = *(const int4*)(vb + (kt + vrow) * 64 + vd0);
        int4 vb2 = *(const int4*)(vb + (kt + vrow + 1) * 64 + vd0);
        int4 mm  = *(const int4*)(mb + srow * S + kt + sc0);
        __syncthreads();
        *(int4*)&Ks[krloc * 72 + sc0] = k0v;
        *(int4*)&Ks[krloc * 72 + sc0 + 8] = k1v;
        {
            const short* ap = (const short*)&va;
            const short* bp = (const short*)&vb2;
#pragma unroll
            for (int j = 0; j < 8; ++j) {
                unsigned pack = (unsigned short)ap[j] | ((unsigned)(unsigned short)bp[j] << 16);
                *(unsigned*)&Vt[(vd0 + j) * 72 + vrow] = pack;
            }
        }
        *(int4*)&Ms[srow * 80 + sc0] = mm;
        __syncthreads();

        // QK^T (keys permuted: tile n, col lr <-> key 4*lr + n)
        f32x4 s[4];
#pragma unroll
        for (int n = 0; n < 4; ++n) s[n] = z;
#pragma unroll
        for (int ks = 0; ks < 2; ++ks) {
#pragma unroll
            for (int n = 0; n < 4; ++n) {
                bf16x8 kf = *(const bf16x8*)&Ks[(n * 16 + lr) * 72 + ks * 32 + lg * 8];
                s[n] = MFMA(qf[ks], kf, s[n]);
            }
        }

        // online softmax, rows 4*lg + r, keys of this lane = 4*lr..4*lr+3
#pragma unroll
        for (int r = 0; r < 4; ++r) {
            unsigned mk = *(const unsigned*)&Ms[(w * 16 + lg * 4 + r) * 80 + lr * 4];
            float s0 = s[0][r], s1 = s[1][r], s2 = s[2][r], s3 = s[3][r];
            float tm = fmaxf(fmaxf(s0, s1), fmaxf(s2, s3));
            tm = fmaxf(tm, __shfl_xor(tm, 1));
            tm = fmaxf(tm, __shfl_xor(tm, 2));
            tm = fmaxf(tm, __shfl_xor(tm, 4));
            tm = fmaxf(tm, __shfl_xor(tm, 8));
            float mn = fmaxf(mi[r], tm);
            float scl = __expf(mi[r] - mn);
            mi[r] = mn;
            float p0 = (mk & 0xffu)       ? __expf(s0 - mn) : 0.f;
            float p1 = (mk & 0xff00u)     ? __expf(s1 - mn) : 0.f;
            float p2 = (mk & 0xff0000u)   ? __expf(s2 - mn) : 0.f;
            float p3 = (mk & 0xff000000u) ? __expf(s3 - mn) : 0.f;
            float rs = (p0 + p1) + (p2 + p3);
            rs += __shfl_xor(rs, 1);
            rs += __shfl_xor(rs, 2);
            rs += __shfl_xor(rs, 4);
            rs += __shfl_xor(rs, 8);
            li[r] = li[r] * scl + rs;
#pragma unroll
            for (int n = 0; n < 4; ++n) oacc[n][r] *= scl;
            s16x4 pk;
            pk.x = f2bf(p0); pk.y = f2bf(p1); pk.z = f2bf(p2); pk.w = f2bf(p3);
            *(s16x4*)&Pw[w][(lg * 4 + r) * 72 + lr * 4] = pk;   // natural key order
        }
        asm volatile("s_waitcnt lgkmcnt(0)" ::: "memory");  // cross-lane P visibility
        __builtin_amdgcn_sched_barrier(0);

        // PV: oacc[n] += P(16x64) * V(64 x d-tile n)
#pragma unroll
        for (int ks = 0; ks < 2; ++ks) {
            bf16x8 pa = *(const bf16x8*)&Pw[w][lr * 72 + ks * 32 + lg * 8];
#pragma unroll
            for (int n = 0; n < 4; ++n) {
                bf16x8 vf = *(const bf16x8*)&Vt[(n * 16 + lr) * 72 + ks * 32 + lg * 8];
                oacc[n] = MFMA(pa, vf, oacc[n]);
            }
        }
    }

    // epilogue: normalize, write context bf16 [B,S,D]
#pragma unroll
    for (int r = 0; r < 4; ++r) {
        float inv = 1.f / li[r];
        int qrow = q0 + w * 16 + lg * 4 + r;
        size_t base = ((size_t)bb * S + qrow) * D + hh * 64;
#pragma unroll
        for (int n = 0; n < 4; ++n)
            hc[base + n * 16 + lr] = f2bf(oacc[n][r] * inv);
    }
}

// ---------------------------------------------------------------------------
// Output projection, bf16 MFMA, fp32 out. grid (128, 16); block 256.
// ---------------------------------------------------------------------------
__global__ __launch_bounds__(256, 2)
void proj_mfma(const short* __restrict__ hb, const short* __restrict__ wfb,
               const float* __restrict__ bfp, float* __restrict__ out)
{
    __shared__ short As[64 * 72];
    __shared__ short Bs[64 * 72];
    const int t = threadIdx.x;
    const int lane = t & 63, w = t >> 6;
    const int lr = lane & 15, lg = lane >> 4;
    const int m0 = blockIdx.x * 64;
    const int n0 = blockIdx.y * 64;
    const int srow = t >> 2, sc0 = (t & 3) * 16;

    f32x4 z = {0.f, 0.f, 0.f, 0.f};
    f32x4 acc[4];
#pragma unroll
    for (int n = 0; n < 4; ++n) acc[n] = z;

    for (int kt = 0; kt < D; kt += 64) {
        const short* ap = hb + (m0 + srow) * D + kt + sc0;
        const short* bp = wfb + (n0 + srow) * D + kt + sc0;
        int4 a0 = *(const int4*)(ap), a1 = *(const int4*)(ap + 8);
        int4 b0 = *(const int4*)(bp), b1 = *(const int4*)(bp + 8);
        __syncthreads();
        *(int4*)&As[srow * 72 + sc0] = a0; *(int4*)&As[srow * 72 + sc0 + 8] = a1;
        *(int4*)&Bs[srow * 72 + sc0] = b0; *(int4*)&Bs[srow * 72 + sc0 + 8] = b1;
        __syncthreads();
#pragma unroll
        for (int ks = 0; ks < 2; ++ks) {
            bf16x8 af = *(const bf16x8*)&As[(w * 16 + lr) * 72 + ks * 32 + lg * 8];
#pragma unroll
            for (int n = 0; n < 4; ++n) {
                bf16x8 bf_ = *(const bf16x8*)&Bs[(n * 16 + lr) * 72 + ks * 32 + lg * 8];
                acc[n] = MFMA(af, bf_, acc[n]);
            }
        }
    }

#pragma unroll
    for (int n = 0; n < 4; ++n) {
        float bi = bfp[n0 + n * 16 + lr];
#pragma unroll
        for (int r = 0; r < 4; ++r) {
            int m = m0 + w * 16 + lg * 4 + r;
            out[(size_t)m * D + n0 + n * 16 + lr] = acc[n][r] + bi;
        }
    }
}

// ---------------------------------------------------------------------------
extern "C" void kernel_launch(void* const* d_in, const int* in_sizes, int n_in,
                              void* d_out, int out_size, void* d_ws, size_t ws_size,
                              hipStream_t stream)
{
    const float* x  = (const float*)d_in[0];
    const int* mask = (const int*)d_in[1];
    const float* Wq = (const float*)d_in[2];
    const float* bq = (const float*)d_in[3];
    const float* Wk = (const float*)d_in[4];
    const float* bk = (const float*)d_in[5];
    const float* Wv = (const float*)d_in[6];
    const float* bv = (const float*)d_in[7];
    const float* Wf = (const float*)d_in[8];
    const float* bf = (const float*)d_in[9];
    float* out = (float*)d_out;

    char* p = (char*)d_ws;
    short* xb  = (short*)p; p += 16777216;                       // x bf16
    short* wqb = (short*)p; p += 2097152;
    short* wkb = (short*)p; p += 2097152;
    short* wvb = (short*)p; p += 2097152;
    short* wfb = (short*)p; p += 2097152;
    unsigned char* mu = (unsigned char*)p; p += 16777216;        // mask u8
    short* qb  = (short*)p; p += 16777216;                       // [B,H,S,HD] bf16
    short* kb  = (short*)p; p += 16777216;
    short* vb  = (short*)p; p += 16777216;
    short* hcb = (short*)p; p += 16777216;                       // [B,S,D] bf16

    conv_pack<<<12288, 256, 0, stream>>>(x, Wq, Wk, Wv, Wf, xb, wqb, wkb, wvb, wfb);
    conv_mask<<<16384, 256, 0, stream>>>(mask, mu);
    qkv_mfma<<<dim3(128, 16), 256, 0, stream>>>(xb, wqb, wkb, wvb, bq, bk, bv, qb, kb, vb);
    attn_mfma<<<dim3(32, 64), 256, 0, stream>>>(qb, kb, vb, mu, hcb);
    proj_mfma<<<dim3(128, 16), 256, 0, stream>>>(hcb, wfb, bf, out);
}

// Round 4
// 264.403 us; speedup vs baseline: 8.6310x; 1.5599x over previous
//
#include <hip/hip_runtime.h>
#include <math.h>

constexpr int S = 2048, D = 1024, H = 16;

typedef __attribute__((ext_vector_type(8))) short bf16x8;
typedef __attribute__((ext_vector_type(4))) short s16x4;
typedef __attribute__((ext_vector_type(4))) float f32x4;
typedef __attribute__((ext_vector_type(16))) float f32x16;

#define MFMA16(a,b,c) __builtin_amdgcn_mfma_f32_16x16x32_bf16(a,b,c,0,0,0)
#define MFMA32(a,b,c) __builtin_amdgcn_mfma_f32_32x32x16_bf16(a,b,c,0,0,0)

#define GLDS16(g, l) __builtin_amdgcn_global_load_lds( \
    (const __attribute__((address_space(1))) unsigned*)(const void*)(g), \
    (__attribute__((address_space(3))) unsigned*)(void*)(l), 16, 0, 0)

__device__ inline short f2bf(float f) {
    union { float f; unsigned u; } c; c.f = f;
    unsigned u = c.u + 0x7fffu + ((c.u >> 16) & 1u);
    return (short)(u >> 16);
}

// ---------------------------------------------------------------------------
// Convert x and the 4 weight matrices to bf16 (RNE).
// ---------------------------------------------------------------------------
__global__ __launch_bounds__(256)
void conv_pack(const float* __restrict__ x,  const float* __restrict__ wq,
               const float* __restrict__ wk, const float* __restrict__ wv,
               const float* __restrict__ wf,
               short* __restrict__ xb,  short* __restrict__ wqb,
               short* __restrict__ wkb, short* __restrict__ wvb,
               short* __restrict__ wfb)
{
    int i = blockIdx.x * 256 + threadIdx.x;
    const float* s; short* d; int o;
    if (i < 2097152) { s = x; d = xb; o = i; }
    else {
        int j = i - 2097152; int wsel = j >> 18; o = j & 262143;
        s = wsel == 0 ? wq : wsel == 1 ? wk : wsel == 2 ? wv : wf;
        d = wsel == 0 ? wqb : wsel == 1 ? wkb : wsel == 2 ? wvb : wfb;
    }
    float4 v = ((const float4*)s)[o];
    s16x4 r; r.x = f2bf(v.x); r.y = f2bf(v.y); r.z = f2bf(v.z); r.w = f2bf(v.w);
    ((s16x4*)d)[o] = r;
}

// ---------------------------------------------------------------------------
// mask int32 -> u64 bitmask per (batch, q-row, 64-key tile). One wave per word.
// ---------------------------------------------------------------------------
__global__ __launch_bounds__(256)
void conv_maskbits(const int* __restrict__ m, unsigned long long* __restrict__ o)
{
    int gw = blockIdx.x * 4 + (threadIdx.x >> 6);
    int lane = threadIdx.x & 63;
    int bb = gw >> 16, rest = gw & 65535;          // rest = s*32 + kt
    const int* src = m + (size_t)bb * S * S + (size_t)(rest >> 5) * S + (rest & 31) * 64 + lane;
    unsigned long long bits = __ballot(*src != 0);
    if (lane == 0) o[(size_t)bb * (S * 32) + rest] = bits;
}

// ---------------------------------------------------------------------------
// Fused QKV GEMM, bf16 MFMA.  y = x @ W^T + b.
// q (pre-scaled 1/8) and k written [B,H,S,HD]; v written TRANSPOSED [B,H,HD,S].
// grid (128, 16); block 256 = 4 waves.
// ---------------------------------------------------------------------------
__global__ __launch_bounds__(256, 2)
void qkv_mfma(const short* __restrict__ xb,
              const short* __restrict__ wqb, const short* __restrict__ wkb,
              const short* __restrict__ wvb,
              const float* __restrict__ bq, const float* __restrict__ bk,
              const float* __restrict__ bv,
              short* __restrict__ qo, short* __restrict__ ko, short* __restrict__ vto)
{
    __shared__ short As[64 * 72];
    __shared__ short Bs[3][64 * 72];
    const int t = threadIdx.x;
    const int lane = t & 63, w = t >> 6;
    const int lr = lane & 15, lg = lane >> 4;
    const int m0 = blockIdx.x * 64;
    const int hh = blockIdx.y;
    const int n0 = hh * 64;
    const int srow = t >> 2, sc0 = (t & 3) * 16;

    f32x4 z = {0.f, 0.f, 0.f, 0.f};
    f32x4 acc[3][4];
#pragma unroll
    for (int m = 0; m < 3; ++m)
#pragma unroll
        for (int n = 0; n < 4; ++n) acc[m][n] = z;

    for (int kt = 0; kt < D; kt += 64) {
        const short* xp = xb + (m0 + srow) * D + kt + sc0;
        const short* qp = wqb + (n0 + srow) * D + kt + sc0;
        const short* kp = wkb + (n0 + srow) * D + kt + sc0;
        const short* vp = wvb + (n0 + srow) * D + kt + sc0;
        int4 a0 = *(const int4*)(xp),     a1 = *(const int4*)(xp + 8);
        int4 q0v = *(const int4*)(qp),    q1v = *(const int4*)(qp + 8);
        int4 k0v = *(const int4*)(kp),    k1v = *(const int4*)(kp + 8);
        int4 v0v = *(const int4*)(vp),    v1v = *(const int4*)(vp + 8);
        __syncthreads();
        *(int4*)&As[srow * 72 + sc0] = a0;     *(int4*)&As[srow * 72 + sc0 + 8] = a1;
        *(int4*)&Bs[0][srow * 72 + sc0] = q0v; *(int4*)&Bs[0][srow * 72 + sc0 + 8] = q1v;
        *(int4*)&Bs[1][srow * 72 + sc0] = k0v; *(int4*)&Bs[1][srow * 72 + sc0 + 8] = k1v;
        *(int4*)&Bs[2][srow * 72 + sc0] = v0v; *(int4*)&Bs[2][srow * 72 + sc0 + 8] = v1v;
        __syncthreads();
#pragma unroll
        for (int ks = 0; ks < 2; ++ks) {
            bf16x8 af = *(const bf16x8*)&As[(w * 16 + lr) * 72 + ks * 32 + lg * 8];
#pragma unroll
            for (int n = 0; n < 4; ++n) {
                bf16x8 b0 = *(const bf16x8*)&Bs[0][(n * 16 + lr) * 72 + ks * 32 + lg * 8];
                acc[0][n] = MFMA16(af, b0, acc[0][n]);
                bf16x8 b1 = *(const bf16x8*)&Bs[1][(n * 16 + lr) * 72 + ks * 32 + lg * 8];
                acc[1][n] = MFMA16(af, b1, acc[1][n]);
                bf16x8 b2 = *(const bf16x8*)&Bs[2][(n * 16 + lr) * 72 + ks * 32 + lg * 8];
                acc[2][n] = MFMA16(af, b2, acc[2][n]);
            }
        }
    }

    const int bb = m0 >> 11;
    const int ss0 = (m0 & (S - 1)) + w * 16 + lg * 4;
    // q (scaled) and k: [B,H,S,HD]
#pragma unroll
    for (int n = 0; n < 4; ++n) {
        float biq = bq[n0 + n * 16 + lr];
        float bik = bk[n0 + n * 16 + lr];
#pragma unroll
        for (int r = 0; r < 4; ++r) {
            const size_t base = (((size_t)bb * H + hh) * S + ss0 + r) * 64 + n * 16 + lr;
            qo[base] = f2bf((acc[0][n][r] + biq) * 0.125f);
            ko[base] = f2bf(acc[1][n][r] + bik);
        }
    }
    // v transposed: [B,H,HD,S] -- 4 consecutive s per lane -> b64 store
#pragma unroll
    for (int n = 0; n < 4; ++n) {
        float biv = bv[n0 + n * 16 + lr];
        s16x4 pk;
#pragma unroll
        for (int r = 0; r < 4; ++r) pk[r] = f2bf(acc[2][n][r] + biv);
        *(s16x4*)(vto + (((size_t)bb * H + hh) * 64 + n * 16 + lr) * S + ss0) = pk;
    }
}

// ---------------------------------------------------------------------------
// Flash attention v2: swapped-QK 32x32 MFMA, in-register softmax.
// Block = 4 waves x 32 q-rows = 128 q. KV tile = 64 keys, double-buffered LDS
// staged via global_load_lds with XOR-swizzled (pre-swizzled-source) layout.
// grid 1024 (XCD-grouped bh), block 256.
// ---------------------------------------------------------------------------
__global__ __launch_bounds__(256, 4)
void attn_mfma2(const short* __restrict__ qg, const short* __restrict__ kg,
                const short* __restrict__ vtg, const unsigned long long* __restrict__ mbits,
                short* __restrict__ hc)
{
    __shared__ short Kl[2][64 * 64];
    __shared__ short Vl[2][64 * 64];

    const int t = threadIdx.x, lane = t & 63, w = t >> 6;
    const int l31 = lane & 31, h = lane >> 5;

    // XCD-aware decode: 16 q-blocks of one bh stay on one XCD
    const int id = blockIdx.x;
    const int xcd = id & 7, j = id >> 3;
    const int bh = xcd + 8 * (j >> 4);
    const int q0 = (j & 15) * 128;
    const int bb = bh >> 4, hh = bh & 15;

    const short* qb  = qg  + (size_t)bh * S * 64;
    const short* kb  = kg  + (size_t)bh * S * 64;
    const short* vtb = vtg + (size_t)bh * 64 * S;
    const unsigned long long* mrow = mbits + ((size_t)bb * S + q0 + w * 32 + l31) * 32;

    // Q fragments (B-operand of swapped QK): lane = q-col (l31), d = ds*16+8h+j
    const int qrow = q0 + w * 32 + l31;
    bf16x8 qf[4];
#pragma unroll
    for (int ds = 0; ds < 4; ++ds)
        qf[ds] = *(const bf16x8*)(qb + (size_t)qrow * 64 + ds * 16 + 8 * h);

    // staging constants: thread t covers LDS bytes [16t,16t+16) (+4096 for rows+32)
    const int sk = t >> 3;                                   // row 0..31
    const int soff = (((t & 7) * 16) ^ ((sk & 7) << 4)) >> 1; // pre-swizzled src elem
    // frag-read constants
    const int rbyte = l31 * 128;
    const int sz = (lane & 7) << 4;

    f32x16 z16;
#pragma unroll
    for (int i = 0; i < 16; ++i) z16[i] = 0.f;

    float mi = -INFINITY, li = 0.f;
    f32x16 O0 = z16, O1 = z16;

    auto issue_stage = [&](int kt, int buf) {
        const short* ks0 = kb + (size_t)(kt + sk) * 64 + soff;
        const short* vs0 = vtb + (size_t)sk * S + kt + soff;
        char* kB = (char*)&Kl[buf][0] + w * 1024;
        char* vB = (char*)&Vl[buf][0] + w * 1024;
        GLDS16(ks0, kB);
        GLDS16(ks0 + 32 * 64, kB + 4096);
        GLDS16(vs0, vB);
        GLDS16(vs0 + (size_t)32 * S, vB + 4096);
    };

    unsigned long long mk = mrow[0], mkn = 0;
    issue_stage(0, 0);
    __syncthreads();

    for (int tile = 0; tile < 32; ++tile) {
        const int cur = tile & 1;
        if (tile < 31) { issue_stage((tile + 1) * 64, cur ^ 1); mkn = mrow[tile + 1]; }

        // ---- QK^T (swapped): s = K . Q^T, lane owns q-row l31, scores col-local
        f32x16 s0 = z16, s1 = z16;
        const char* Kb = (const char*)&Kl[cur][0];
#pragma unroll
        for (int ds = 0; ds < 4; ++ds) {
            const int off = ((ds * 32 + h * 16) ^ sz);
            bf16x8 a0 = *(const bf16x8*)(Kb + rbyte + off);
            bf16x8 a1 = *(const bf16x8*)(Kb + 4096 + rbyte + off);
            s0 = MFMA32(a0, qf[ds], s0);
            s1 = MFMA32(a1, qf[ds], s1);
        }

        // ---- tile max over raw scores (mask keeps distribution; m-hat >= m ok)
        float tm = s0[0];
#pragma unroll
        for (int r = 1; r < 16; ++r) tm = fmaxf(tm, s0[r]);
#pragma unroll
        for (int r = 0; r < 16; ++r) tm = fmaxf(tm, s1[r]);
        tm = fmaxf(tm, __shfl_xor(tm, 32));

        // ---- defer-max rescale (T13): triggers ~once per block
        if (!__all(tm - mi <= 8.f)) {
            float mn = fmaxf(mi, tm);
            float scl = __expf(mi - mn);
            mi = mn;
            li *= scl;
#pragma unroll
            for (int r = 0; r < 16; ++r) {
                const int qp = (r & 3) + 8 * (r >> 2);
                int slo = __builtin_amdgcn_readlane(__builtin_bit_cast(int, scl), qp);
                int shi = __builtin_amdgcn_readlane(__builtin_bit_cast(int, scl), qp + 4);
                float sr = h ? __builtin_bit_cast(float, shi) : __builtin_bit_cast(float, slo);
                O0[r] *= sr; O1[r] *= sr;
            }
        }

        // ---- p = keep ? exp(s - mi) : 0 ; accumulate partial li
        {
            unsigned long long mh = mk >> (4 * h);
            unsigned wlo = (unsigned)mh, whi = (unsigned)(mh >> 32);
            float ls = 0.f;
#pragma unroll
            for (int r = 0; r < 16; ++r) {
                const int bit = (r & 3) + 8 * (r >> 2);
                float p0 = __expf(s0[r] - mi);
                float p1 = __expf(s1[r] - mi);
                p0 = ((wlo >> bit) & 1u) ? p0 : 0.f;
                p1 = ((whi >> bit) & 1u) ? p1 : 0.f;
                s0[r] = p0; s1[r] = p1;
                ls += p0 + p1;
            }
            li += ls;
        }

        // ---- P fragments in-register (cvt_pk + permlane32_swap), then PV
        const char* Vb = (const char*)&Vl[cur][0];
#pragma unroll
        for (int ks = 0; ks < 4; ++ks) {
            float a0, a1, a2, a3, b0, b1, b2, b3;
            if (ks < 2) {               // groups from s0 (keys 0..31)
                const int rb = 2 * ks * 4;
                a0 = s0[rb]; a1 = s0[rb + 1]; a2 = s0[rb + 2]; a3 = s0[rb + 3];
                b0 = s0[rb + 4]; b1 = s0[rb + 5]; b2 = s0[rb + 6]; b3 = s0[rb + 7];
            } else {                    // groups from s1 (keys 32..63)
                const int rb = 2 * (ks - 2) * 4;
                a0 = s1[rb]; a1 = s1[rb + 1]; a2 = s1[rb + 2]; a3 = s1[rb + 3];
                b0 = s1[rb + 4]; b1 = s1[rb + 5]; b2 = s1[rb + 6]; b3 = s1[rb + 7];
            }
            int w0a, w1a, w0b, w1b;
            asm("v_cvt_pk_bf16_f32 %0, %1, %2" : "=v"(w0a) : "v"(a0), "v"(a1));
            asm("v_cvt_pk_bf16_f32 %0, %1, %2" : "=v"(w1a) : "v"(a2), "v"(a3));
            asm("v_cvt_pk_bf16_f32 %0, %1, %2" : "=v"(w0b) : "v"(b0), "v"(b1));
            asm("v_cvt_pk_bf16_f32 %0, %1, %2" : "=v"(w1b) : "v"(b2), "v"(b3));
            asm("v_permlane32_swap_b32 %0, %1" : "+v"(w0a), "+v"(w0b));
            asm("v_permlane32_swap_b32 %0, %1" : "+v"(w1a), "+v"(w1b));
            union { int i[4]; bf16x8 v; } pf;
            pf.i[0] = w0a; pf.i[1] = w1a; pf.i[2] = w0b; pf.i[3] = w1b;

            const int koff = ((ks * 32 + h * 16) ^ sz);
            bf16x8 v0 = *(const bf16x8*)(Vb + rbyte + koff);
            bf16x8 v1 = *(const bf16x8*)(Vb + 4096 + rbyte + koff);
            O0 = MFMA32(pf.v, v0, O0);
            O1 = MFMA32(pf.v, v1, O1);
        }

        if (tile < 31) mk = mkn;
        __syncthreads();
    }

    // ---- epilogue: combine half-lane li, normalize, store [B,S,D] bf16
    float lo = __shfl_xor(li, 32);
    float inv = 1.f / (li + lo);
    const size_t outb = (size_t)bb * S * D + (size_t)hh * 64;
#pragma unroll
    for (int r = 0; r < 16; ++r) {
        const int qp = (r & 3) + 8 * (r >> 2);
        int ilo = __builtin_amdgcn_readlane(__builtin_bit_cast(int, inv), qp);
        int ihi = __builtin_amdgcn_readlane(__builtin_bit_cast(int, inv), qp + 4);
        float ir = h ? __builtin_bit_cast(float, ihi) : __builtin_bit_cast(float, ilo);
        const int row = q0 + w * 32 + qp + 4 * h;
        hc[outb + (size_t)row * D + l31] = f2bf(O0[r] * ir);
        hc[outb + (size_t)row * D + 32 + l31] = f2bf(O1[r] * ir);
    }
}

// ---------------------------------------------------------------------------
// Output projection, bf16 MFMA, fp32 out. grid (128, 16); block 256.
// ---------------------------------------------------------------------------
__global__ __launch_bounds__(256, 2)
void proj_mfma(const short* __restrict__ hb, const short* __restrict__ wfb,
               const float* __restrict__ bfp, float* __restrict__ out)
{
    __shared__ short As[64 * 72];
    __shared__ short Bs[64 * 72];
    const int t = threadIdx.x;
    const int lane = t & 63, w = t >> 6;
    const int lr = lane & 15, lg = lane >> 4;
    const int m0 = blockIdx.x * 64;
    const int n0 = blockIdx.y * 64;
    const int srow = t >> 2, sc0 = (t & 3) * 16;

    f32x4 z = {0.f, 0.f, 0.f, 0.f};
    f32x4 acc[4];
#pragma unroll
    for (int n = 0; n < 4; ++n) acc[n] = z;

    for (int kt = 0; kt < D; kt += 64) {
        const short* ap = hb + (m0 + srow) * D + kt + sc0;
        const short* bp = wfb + (n0 + srow) * D + kt + sc0;
        int4 a0 = *(const int4*)(ap), a1 = *(const int4*)(ap + 8);
        int4 b0 = *(const int4*)(bp), b1 = *(const int4*)(bp + 8);
        __syncthreads();
        *(int4*)&As[srow * 72 + sc0] = a0; *(int4*)&As[srow * 72 + sc0 + 8] = a1;
        *(int4*)&Bs[srow * 72 + sc0] = b0; *(int4*)&Bs[srow * 72 + sc0 + 8] = b1;
        __syncthreads();
#pragma unroll
        for (int ks = 0; ks < 2; ++ks) {
            bf16x8 af = *(const bf16x8*)&As[(w * 16 + lr) * 72 + ks * 32 + lg * 8];
#pragma unroll
            for (int n = 0; n < 4; ++n) {
                bf16x8 bf_ = *(const bf16x8*)&Bs[(n * 16 + lr) * 72 + ks * 32 + lg * 8];
                acc[n] = MFMA16(af, bf_, acc[n]);
            }
        }
    }

#pragma unroll
    for (int n = 0; n < 4; ++n) {
        float bi = bfp[n0 + n * 16 + lr];
#pragma unroll
        for (int r = 0; r < 4; ++r) {
            int m = m0 + w * 16 + lg * 4 + r;
            out[(size_t)m * D + n0 + n * 16 + lr] = acc[n][r] + bi;
        }
    }
}

// ---------------------------------------------------------------------------
extern "C" void kernel_launch(void* const* d_in, const int* in_sizes, int n_in,
                              void* d_out, int out_size, void* d_ws, size_t ws_size,
                              hipStream_t stream)
{
    const float* x  = (const float*)d_in[0];
    const int* mask = (const int*)d_in[1];
    const float* Wq = (const float*)d_in[2];
    const float* bq = (const float*)d_in[3];
    const float* Wk = (const float*)d_in[4];
    const float* bk = (const float*)d_in[5];
    const float* Wv = (const float*)d_in[6];
    const float* bv = (const float*)d_in[7];
    const float* Wf = (const float*)d_in[8];
    const float* bf = (const float*)d_in[9];
    float* out = (float*)d_out;

    char* p = (char*)d_ws;
    short* xb  = (short*)p; p += 16777216;                       // x bf16
    short* wqb = (short*)p; p += 2097152;
    short* wkb = (short*)p; p += 2097152;
    short* wvb = (short*)p; p += 2097152;
    short* wfb = (short*)p; p += 2097152;
    unsigned long long* mbits = (unsigned long long*)p; p += 2097152;  // bitmask
    short* qb  = (short*)p; p += 16777216;                       // [B,H,S,HD]
    short* kb  = (short*)p; p += 16777216;                       // [B,H,S,HD]
    short* vtb = (short*)p; p += 16777216;                       // [B,H,HD,S]
    short* hcb = (short*)p; p += 16777216;                       // [B,S,D]

    conv_pack<<<12288, 256, 0, stream>>>(x, Wq, Wk, Wv, Wf, xb, wqb, wkb, wvb, wfb);
    conv_maskbits<<<65536, 256, 0, stream>>>(mask, mbits);
    qkv_mfma<<<dim3(128, 16), 256, 0, stream>>>(xb, wqb, wkb, wvb, bq, bk, bv, qb, kb, vtb);
    attn_mfma2<<<1024, 256, 0, stream>>>(qb, kb, vtb, mbits, hcb);
    proj_mfma<<<dim3(128, 16), 256, 0, stream>>>(hcb, wfb, bf, out);
}

// Round 8
// 230.956 us; speedup vs baseline: 9.8810x; 1.1448x over previous
//
#include <hip/hip_runtime.h>
#include <math.h>

constexpr int S = 2048, D = 1024, H = 16;
constexpr float QSCL = 0.18033688011112042f;   // log2(e) / sqrt(64)

typedef __attribute__((ext_vector_type(8))) short bf16x8;
typedef __attribute__((ext_vector_type(4))) short s16x4;
typedef __attribute__((ext_vector_type(4))) float f32x4;
typedef __attribute__((ext_vector_type(16))) float f32x16;

#define MFMA16(a,b,c) __builtin_amdgcn_mfma_f32_16x16x32_bf16(a,b,c,0,0,0)
#define MFMA32(a,b,c) __builtin_amdgcn_mfma_f32_32x32x16_bf16(a,b,c,0,0,0)

#define GLDS16(g, l) __builtin_amdgcn_global_load_lds( \
    (const __attribute__((address_space(1))) unsigned*)(const void*)(g), \
    (__attribute__((address_space(3))) unsigned*)(void*)(l), 16, 0, 0)

__device__ inline short f2bf(float f) {
    union { float f; unsigned u; } c; c.f = f;
    unsigned u = c.u + 0x7fffu + ((c.u >> 16) & 1u);
    return (short)(u >> 16);
}

// ---------------------------------------------------------------------------
// Convert x and the 4 weight matrices to bf16 (RNE). wq..wf land contiguous.
// ---------------------------------------------------------------------------
__global__ __launch_bounds__(256)
void conv_pack(const float* __restrict__ x,  const float* __restrict__ wq,
               const float* __restrict__ wk, const float* __restrict__ wv,
               const float* __restrict__ wf,
               short* __restrict__ xb,  short* __restrict__ wqb,
               short* __restrict__ wkb, short* __restrict__ wvb,
               short* __restrict__ wfb)
{
    int i = blockIdx.x * 256 + threadIdx.x;
    const float* s; short* d; int o;
    if (i < 2097152) { s = x; d = xb; o = i; }
    else {
        int j = i - 2097152; int wsel = j >> 18; o = j & 262143;
        s = wsel == 0 ? wq : wsel == 1 ? wk : wsel == 2 ? wv : wf;
        d = wsel == 0 ? wqb : wsel == 1 ? wkb : wsel == 2 ? wvb : wfb;
    }
    float4 v = ((const float4*)s)[o];
    s16x4 r; r.x = f2bf(v.x); r.y = f2bf(v.y); r.z = f2bf(v.z); r.w = f2bf(v.w);
    ((s16x4*)d)[o] = r;
}

// ---------------------------------------------------------------------------
// Per-lane mask column words: u32 at [(bb*64+grp)*32 + tile]*64 + lane,
// bit r = mask[bb][grp*32 + (lane&31)][tile*64 + (r&3) + 8*((r>>2)&3)
//                                       + 32*(r>>4) + 4*(lane>>5)] != 0
// (bit 4a+i <-> key 8*(a&3) + 32*(a>>2) + 4h + i, identical formula)
// ---------------------------------------------------------------------------
__global__ __launch_bounds__(256)
void conv_maskcol(const int* __restrict__ m, unsigned* __restrict__ o)
{
    int gid = blockIdx.x * 256 + threadIdx.x;      // 2048 blocks -> 524288
    int lane = gid & 63;
    int tile = (gid >> 6) & 31;
    int grp  = (gid >> 11) & 63;
    int bb   = gid >> 17;
    int qrow = grp * 32 + (lane & 31);
    int h = lane >> 5;
    const int* base = m + (size_t)bb * S * S + (size_t)qrow * S + tile * 64 + 4 * h;
    unsigned wbits = 0;
#pragma unroll
    for (int a = 0; a < 8; ++a) {
        int4 v = *(const int4*)(base + 8 * (a & 3) + 32 * (a >> 2));
        wbits |= (v.x != 0 ? 1u : 0u) << (4 * a);
        wbits |= (v.y != 0 ? 1u : 0u) << (4 * a + 1);
        wbits |= (v.z != 0 ? 1u : 0u) << (4 * a + 2);
        wbits |= (v.w != 0 ? 1u : 0u) << (4 * a + 3);
    }
    o[gid] = wbits;
}

// ---------------------------------------------------------------------------
// Fused QKV GEMM, 128x128 tile, BK=64, global_load_lds + XOR swizzle.
// C[8192,3072] = x @ [Wq;Wk;Wv]^T. grid (64, 24); block 256 = 4 waves (2x2).
// Epilogue: q scaled by log2e/8 -> [B,H,S,64]; k -> [B,H,S,64]; v -> [B,H,64,S].
// ---------------------------------------------------------------------------
__global__ __launch_bounds__(256, 3)
void qkv_mfma(const short* __restrict__ xb, const short* __restrict__ wcat,
              const float* __restrict__ bq, const float* __restrict__ bk,
              const float* __restrict__ bv,
              short* __restrict__ qo, short* __restrict__ ko, short* __restrict__ vto)
{
    __shared__ short As[128 * 64];
    __shared__ short Bs[128 * 64];
    const int t = threadIdx.x, lane = t & 63;
    const int w = __builtin_amdgcn_readfirstlane(t >> 6);
    const int lr = lane & 15, lg = lane >> 4;
    const int wr = w >> 1, wc = w & 1;
    const int m0 = blockIdx.x * 128, n0 = blockIdx.y * 128;

    const int srow = t >> 3;                            // 0..31
    const int scol = ((t & 7) ^ (srow & 7)) * 8;        // pre-swizzled col group
    const short* asrc = xb   + (size_t)(m0 + srow) * 1024 + scol;
    const short* bsrc = wcat + (size_t)(n0 + srow) * 1024 + scol;
    char* aldst = (char*)As + w * 1024;                 // HW adds lane*16
    char* bldst = (char*)Bs + w * 1024;

    f32x4 z = {0.f, 0.f, 0.f, 0.f};
    f32x4 acc[4][4];
#pragma unroll
    for (int i = 0; i < 4; ++i)
#pragma unroll
        for (int jj = 0; jj < 4; ++jj) acc[i][jj] = z;

    for (int kt = 0; kt < 1024; kt += 64) {
        __syncthreads();
        // each GLDS call covers 4096 B (32 rows of 128 B) across the block
        GLDS16(asrc + kt,             aldst);
        GLDS16(asrc + kt + 32 * 1024, aldst + 4096);
        GLDS16(asrc + kt + 64 * 1024, aldst + 8192);
        GLDS16(asrc + kt + 96 * 1024, aldst + 12288);
        GLDS16(bsrc + kt,             bldst);
        GLDS16(bsrc + kt + 32 * 1024, bldst + 4096);
        GLDS16(bsrc + kt + 64 * 1024, bldst + 8192);
        GLDS16(bsrc + kt + 96 * 1024, bldst + 12288);
        __syncthreads();
#pragma unroll
        for (int ks = 0; ks < 2; ++ks) {
            bf16x8 af[4], bfr[4];
#pragma unroll
            for (int fi = 0; fi < 4; ++fi) {
                const int ra = wr * 64 + fi * 16 + lr;
                af[fi] = *(const bf16x8*)((const char*)As + ra * 128 +
                          ((ks * 64 + lg * 16) ^ ((ra & 7) << 4)));
                const int rb = wc * 64 + fi * 16 + lr;
                bfr[fi] = *(const bf16x8*)((const char*)Bs + rb * 128 +
                          ((ks * 64 + lg * 16) ^ ((rb & 7) << 4)));
            }
#pragma unroll
            for (int fi = 0; fi < 4; ++fi)
#pragma unroll
                for (int fj = 0; fj < 4; ++fj)
                    acc[fi][fj] = MFMA16(af[fi], bfr[fj], acc[fi][fj]);
        }
    }

    const int bb = m0 >> 11;
    const int ssb = (m0 & (S - 1)) + wr * 64 + lg * 4;
    const int mat = n0 >> 10;
    const int nbase = (n0 & 1023) + wc * 64;

    if (mat == 0) {
#pragma unroll
        for (int fj = 0; fj < 4; ++fj) {
            const int nl = nbase + fj * 16 + lr, hh = nl >> 6, hd = nl & 63;
            const float bi = bq[nl];
#pragma unroll
            for (int fi = 0; fi < 4; ++fi)
#pragma unroll
                for (int r = 0; r < 4; ++r)
                    qo[(((size_t)bb * H + hh) * S + ssb + fi * 16 + r) * 64 + hd] =
                        f2bf((acc[fi][fj][r] + bi) * QSCL);
        }
    } else if (mat == 1) {
#pragma unroll
        for (int fj = 0; fj < 4; ++fj) {
            const int nl = nbase + fj * 16 + lr, hh = nl >> 6, hd = nl & 63;
            const float bi = bk[nl];
#pragma unroll
            for (int fi = 0; fi < 4; ++fi)
#pragma unroll
                for (int r = 0; r < 4; ++r)
                    ko[(((size_t)bb * H + hh) * S + ssb + fi * 16 + r) * 64 + hd] =
                        f2bf(acc[fi][fj][r] + bi);
        }
    } else {
#pragma unroll
        for (int fj = 0; fj < 4; ++fj) {
            const int nl = nbase + fj * 16 + lr, hh = nl >> 6, hd = nl & 63;
            const float bi = bv[nl];
#pragma unroll
            for (int fi = 0; fi < 4; ++fi) {
                s16x4 pk;
#pragma unroll
                for (int r = 0; r < 4; ++r) pk[r] = f2bf(acc[fi][fj][r] + bi);
                *(s16x4*)(vto + (((size_t)bb * H + hh) * 64 + hd) * S + ssb + fi * 16) = pk;
            }
        }
    }
}

// ---------------------------------------------------------------------------
// Flash attention v4: swapped-QK 32x32 MFMA, p = exp2f(mask ? s : -inf),
// all-compiler softmax path; cvt_pk+permlane pack (R4-proven); Lacc via
// MFMA-with-ones. 4 waves x 32 q = 128 q. grid 1024 (XCD-grouped).
// ---------------------------------------------------------------------------
__global__ __launch_bounds__(256, 3)
void attn_mfma4(const short* __restrict__ qg, const short* __restrict__ kg,
                const short* __restrict__ vtg,
                const unsigned* __restrict__ mcol,
                short* __restrict__ hc)
{
    __shared__ short Kl[2][64 * 64];
    __shared__ short Vl[2][64 * 64];

    const int t = threadIdx.x, lane = t & 63;
    const int w = __builtin_amdgcn_readfirstlane(t >> 6);
    const int l31 = lane & 31, h = lane >> 5;

    const int id = blockIdx.x;
    const int xcd = id & 7, j = id >> 3;
    const int bh = xcd + 8 * (j >> 4);
    const int q0 = (j & 15) * 128;
    const int bb = bh >> 4, hh = bh & 15;

    const short* qb  = qg  + (size_t)bh * S * 64;
    const short* kb  = kg  + (size_t)bh * S * 64;
    const short* vtb = vtg + (size_t)bh * 64 * S;
    const unsigned* mc = mcol + ((size_t)(bb * 64 + (q0 >> 5) + w)) * 32 * 64 + lane;

    const int qrow = q0 + w * 32 + l31;
    bf16x8 qf[4];
#pragma unroll
    for (int ds = 0; ds < 4; ++ds)
        qf[ds] = *(const bf16x8*)(qb + (size_t)qrow * 64 + ds * 16 + 8 * h);

    const int sk = t >> 3;                                    // staging row 0..31
    const int soff = (((t & 7) * 16) ^ ((sk & 7) << 4)) >> 1; // pre-swizzled src elem
    const int rbyte = l31 * 128;
    const int sz = (lane & 7) << 4;

    f32x16 z16;
#pragma unroll
    for (int i = 0; i < 16; ++i) z16[i] = 0.f;
    f32x16 O0 = z16, O1 = z16, Lacc = z16;

    bf16x8 ones;
#pragma unroll
    for (int i = 0; i < 8; ++i) ones[i] = (short)0x3F80;

    auto issue_stage = [&](int kt, int buf) {
        const short* ks0 = kb + (size_t)(kt + sk) * 64 + soff;
        const short* vs0 = vtb + (size_t)sk * S + kt + soff;
        char* kB = (char*)&Kl[buf][0] + w * 1024;
        char* vB = (char*)&Vl[buf][0] + w * 1024;
        GLDS16(ks0, kB);
        GLDS16(ks0 + 32 * 64, kB + 4096);
        GLDS16(vs0, vB);
        GLDS16(vs0 + (size_t)32 * S, vB + 4096);
    };

    issue_stage(0, 0);
    __syncthreads();

    for (int tile = 0; tile < 32; ++tile) {
        const int cur = tile & 1;
        if (tile < 31) issue_stage((tile + 1) * 64, cur ^ 1);
        const unsigned mcw = mc[tile * 64];

        // ---- QK^T (swapped): lane owns q-row l31; acc starts at 0
        f32x16 s0 = z16, s1 = z16;
        const char* Kb = (const char*)&Kl[cur][0];
#pragma unroll
        for (int ds = 0; ds < 4; ++ds) {
            const int off = ((ds * 32 + h * 16) ^ sz);
            bf16x8 a0 = *(const bf16x8*)(Kb + rbyte + off);
            bf16x8 a1 = *(const bf16x8*)(Kb + 4096 + rbyte + off);
            s0 = MFMA32(a0, qf[ds], s0);
            s1 = MFMA32(a1, qf[ds], s1);
        }

        // ---- p = exp2(mask ? s : -inf) ; pack ; PV + li accumulate
        const char* Vb = (const char*)&Vl[cur][0];
#pragma unroll
        for (int ks = 0; ks < 4; ++ks) {
            const int rb = (ks < 2) ? ks * 8 : (ks - 2) * 8;
            const int wb = (ks < 2) ? rb : 16 + rb;
            float pv[8];
#pragma unroll
            for (int jj = 0; jj < 8; ++jj) {
                float sv = (ks < 2) ? s0[rb + jj] : s1[rb + jj];
                sv = (mcw & (1u << (wb + jj))) ? sv : -INFINITY;
                pv[jj] = exp2f(sv);        // exp2f(-inf) == 0 exactly
            }
            int w0a, w1a, w0b, w1b;
            asm("v_cvt_pk_bf16_f32 %0, %1, %2" : "=v"(w0a) : "v"(pv[0]), "v"(pv[1]));
            asm("v_cvt_pk_bf16_f32 %0, %1, %2" : "=v"(w1a) : "v"(pv[2]), "v"(pv[3]));
            asm("v_cvt_pk_bf16_f32 %0, %1, %2" : "=v"(w0b) : "v"(pv[4]), "v"(pv[5]));
            asm("v_cvt_pk_bf16_f32 %0, %1, %2" : "=v"(w1b) : "v"(pv[6]), "v"(pv[7]));
            asm("v_permlane32_swap_b32 %0, %1" : "+v"(w0a), "+v"(w0b));
            asm("v_permlane32_swap_b32 %0, %1" : "+v"(w1a), "+v"(w1b));
            union { int i[4]; bf16x8 v; } pf;
            pf.i[0] = w0a; pf.i[1] = w1a; pf.i[2] = w0b; pf.i[3] = w1b;

            const int koff = ((ks * 32 + h * 16) ^ sz);
            bf16x8 v0 = *(const bf16x8*)(Vb + rbyte + koff);
            bf16x8 v1 = *(const bf16x8*)(Vb + 4096 + rbyte + koff);
            O0 = MFMA32(pf.v, v0, O0);
            O1 = MFMA32(pf.v, v1, O1);
            Lacc = MFMA32(pf.v, ones, Lacc);
        }
        __syncthreads();
    }

    // ---- epilogue: Lacc[r] is this lane's row-sum; normalize and store
    const size_t outb = (size_t)bb * S * D + (size_t)hh * 64;
#pragma unroll
    for (int r = 0; r < 16; ++r) {
        const float inv = 1.f / Lacc[r];
        const int row = q0 + w * 32 + (r & 3) + 8 * (r >> 2) + 4 * h;
        hc[outb + (size_t)row * D + l31]      = f2bf(O0[r] * inv);
        hc[outb + (size_t)row * D + 32 + l31] = f2bf(O1[r] * inv);
    }
}

// ---------------------------------------------------------------------------
// Output projection, 128x128 tile, fp32 out. grid (64, 8); block 256.
// ---------------------------------------------------------------------------
__global__ __launch_bounds__(256, 3)
void proj_mfma(const short* __restrict__ hb, const short* __restrict__ wfb,
               const float* __restrict__ bfp, float* __restrict__ out)
{
    __shared__ short As[128 * 64];
    __shared__ short Bs[128 * 64];
    const int t = threadIdx.x, lane = t & 63;
    const int w = __builtin_amdgcn_readfirstlane(t >> 6);
    const int lr = lane & 15, lg = lane >> 4;
    const int wr = w >> 1, wc = w & 1;
    const int m0 = blockIdx.x * 128, n0 = blockIdx.y * 128;

    const int srow = t >> 3;
    const int scol = ((t & 7) ^ (srow & 7)) * 8;
    const short* asrc = hb  + (size_t)(m0 + srow) * 1024 + scol;
    const short* bsrc = wfb + (size_t)(n0 + srow) * 1024 + scol;
    char* aldst = (char*)As + w * 1024;
    char* bldst = (char*)Bs + w * 1024;

    f32x4 z = {0.f, 0.f, 0.f, 0.f};
    f32x4 acc[4][4];
#pragma unroll
    for (int i = 0; i < 4; ++i)
#pragma unroll
        for (int jj = 0; jj < 4; ++jj) acc[i][jj] = z;

    for (int kt = 0; kt < 1024; kt += 64) {
        __syncthreads();
        GLDS16(asrc + kt,             aldst);
        GLDS16(asrc + kt + 32 * 1024, aldst + 4096);
        GLDS16(asrc + kt + 64 * 1024, aldst + 8192);
        GLDS16(asrc + kt + 96 * 1024, aldst + 12288);
        GLDS16(bsrc + kt,             bldst);
        GLDS16(bsrc + kt + 32 * 1024, bldst + 4096);
        GLDS16(bsrc + kt + 64 * 1024, bldst + 8192);
        GLDS16(bsrc + kt + 96 * 1024, bldst + 12288);
        __syncthreads();
#pragma unroll
        for (int ks = 0; ks < 2; ++ks) {
            bf16x8 af[4], bfr[4];
#pragma unroll
            for (int fi = 0; fi < 4; ++fi) {
                const int ra = wr * 64 + fi * 16 + lr;
                af[fi] = *(const bf16x8*)((const char*)As + ra * 128 +
                          ((ks * 64 + lg * 16) ^ ((ra & 7) << 4)));
                const int rb = wc * 64 + fi * 16 + lr;
                bfr[fi] = *(const bf16x8*)((const char*)Bs + rb * 128 +
                          ((ks * 64 + lg * 16) ^ ((rb & 7) << 4)));
            }
#pragma unroll
            for (int fi = 0; fi < 4; ++fi)
#pragma unroll
                for (int fj = 0; fj < 4; ++fj)
                    acc[fi][fj] = MFMA16(af[fi], bfr[fj], acc[fi][fj]);
        }
    }

#pragma unroll
    for (int fj = 0; fj < 4; ++fj) {
        const int nl = n0 + wc * 64 + fj * 16 + lr;
        const float bi = bfp[nl];
#pragma unroll
        for (int fi = 0; fi < 4; ++fi)
#pragma unroll
            for (int r = 0; r < 4; ++r)
                out[(size_t)(m0 + wr * 64 + fi * 16 + lg * 4 + r) * 1024 + nl] =
                    acc[fi][fj][r] + bi;
    }
}

// ---------------------------------------------------------------------------
extern "C" void kernel_launch(void* const* d_in, const int* in_sizes, int n_in,
                              void* d_out, int out_size, void* d_ws, size_t ws_size,
                              hipStream_t stream)
{
    const float* x  = (const float*)d_in[0];
    const int* mask = (const int*)d_in[1];
    const float* Wq = (const float*)d_in[2];
    const float* bq = (const float*)d_in[3];
    const float* Wk = (const float*)d_in[4];
    const float* bk = (const float*)d_in[5];
    const float* Wv = (const float*)d_in[6];
    const float* bv = (const float*)d_in[7];
    const float* Wf = (const float*)d_in[8];
    const float* bf = (const float*)d_in[9];
    float* out = (float*)d_out;

    char* p = (char*)d_ws;
    short* xb  = (short*)p; p += 16777216;                       // x bf16
    short* wqb = (short*)p; p += 2097152;                        // [Wq;Wk;Wv;Wf] bf16
    short* wkb = (short*)p; p += 2097152;
    short* wvb = (short*)p; p += 2097152;
    short* wfb = (short*)p; p += 2097152;
    unsigned* mcol = (unsigned*)p; p += 2097152;                 // mask column words
    short* qb  = (short*)p; p += 16777216;                       // [B,H,S,64]
    short* kb  = (short*)p; p += 16777216;                       // [B,H,S,64]
    short* vtb = (short*)p; p += 16777216;                       // [B,H,64,S]
    short* hcb = (short*)p; p += 16777216;                       // [B,S,D]

    conv_pack<<<12288, 256, 0, stream>>>(x, Wq, Wk, Wv, Wf, xb, wqb, wkb, wvb, wfb);
    conv_maskcol<<<2048, 256, 0, stream>>>(mask, mcol);
    qkv_mfma<<<dim3(64, 24), 256, 0, stream>>>(xb, wqb, bq, bk, bv, qb, kb, vtb);
    attn_mfma4<<<1024, 256, 0, stream>>>(qb, kb, vtb, mcol, hcb);
    proj_mfma<<<dim3(64, 8), 256, 0, stream>>>(hcb, wfb, bf, out);
}

// Round 9
// 218.526 us; speedup vs baseline: 10.4430x; 1.0569x over previous
//
#include <hip/hip_runtime.h>
#include <math.h>

constexpr int S = 2048, D = 1024, H = 16;
constexpr float QSCL = 0.18033688011112042f;   // log2(e) / sqrt(64)

typedef __attribute__((ext_vector_type(8))) short bf16x8;
typedef __attribute__((ext_vector_type(4))) short s16x4;
typedef __attribute__((ext_vector_type(4))) float f32x4;
typedef __attribute__((ext_vector_type(16))) float f32x16;

#define MFMA16(a,b,c) __builtin_amdgcn_mfma_f32_16x16x32_bf16(a,b,c,0,0,0)
#define MFMA32(a,b,c) __builtin_amdgcn_mfma_f32_32x32x16_bf16(a,b,c,0,0,0)

#if __has_builtin(__builtin_amdgcn_exp2f)
#define EXP2(x) __builtin_amdgcn_exp2f(x)
#else
#define EXP2(x) exp2f(x)
#endif

#define GLDS16(g, l) __builtin_amdgcn_global_load_lds( \
    (const __attribute__((address_space(1))) unsigned*)(const void*)(g), \
    (__attribute__((address_space(3))) unsigned*)(void*)(l), 16, 0, 0)

__device__ inline short f2bf(float f) {
    union { float f; unsigned u; } c; c.f = f;
    unsigned u = c.u + 0x7fffu + ((c.u >> 16) & 1u);
    return (short)(u >> 16);
}

// ---------------------------------------------------------------------------
// Convert x and the 4 weight matrices to bf16 (RNE). wq..wf land contiguous.
// ---------------------------------------------------------------------------
__global__ __launch_bounds__(256)
void conv_pack(const float* __restrict__ x,  const float* __restrict__ wq,
               const float* __restrict__ wk, const float* __restrict__ wv,
               const float* __restrict__ wf,
               short* __restrict__ xb,  short* __restrict__ wqb,
               short* __restrict__ wkb, short* __restrict__ wvb,
               short* __restrict__ wfb)
{
    int i = blockIdx.x * 256 + threadIdx.x;
    const float* s; short* d; int o;
    if (i < 2097152) { s = x; d = xb; o = i; }
    else {
        int j = i - 2097152; int wsel = j >> 18; o = j & 262143;
        s = wsel == 0 ? wq : wsel == 1 ? wk : wsel == 2 ? wv : wf;
        d = wsel == 0 ? wqb : wsel == 1 ? wkb : wsel == 2 ? wvb : wfb;
    }
    float4 v = ((const float4*)s)[o];
    s16x4 r; r.x = f2bf(v.x); r.y = f2bf(v.y); r.z = f2bf(v.z); r.w = f2bf(v.w);
    ((s16x4*)d)[o] = r;
}

// ---------------------------------------------------------------------------
// Per-lane mask column words (fallback path). Bit r of word(lane) =
// mask[bb][grp*32+(lane&31)][tile*64 + (r&3)+8*((r>>2)&3)+32*(r>>4)+4*(lane>>5)]
// ---------------------------------------------------------------------------
__global__ __launch_bounds__(256)
void conv_maskcol(const int* __restrict__ m, unsigned* __restrict__ o)
{
    int gid = blockIdx.x * 256 + threadIdx.x;      // 2048 blocks -> 524288
    int lane = gid & 63;
    int tile = (gid >> 6) & 31;
    int grp  = (gid >> 11) & 63;
    int bb   = gid >> 17;
    int qrow = grp * 32 + (lane & 31);
    int h = lane >> 5;
    const int* base = m + (size_t)bb * S * S + (size_t)qrow * S + tile * 64 + 4 * h;
    unsigned wbits = 0;
#pragma unroll
    for (int a = 0; a < 8; ++a) {
        int4 v = *(const int4*)(base + 8 * (a & 3) + 32 * (a >> 2));
        wbits |= (v.x != 0 ? 1u : 0u) << (4 * a);
        wbits |= (v.y != 0 ? 1u : 0u) << (4 * a + 1);
        wbits |= (v.z != 0 ? 1u : 0u) << (4 * a + 2);
        wbits |= (v.w != 0 ? 1u : 0u) << (4 * a + 3);
    }
    o[gid] = wbits;
}

// ---------------------------------------------------------------------------
// Mask bias A-fragments (frag path): per (b, qgrp32, ktile32) a 32x32 block of
// bf16 {0 keep, -2992 masked} in MFMA32 A-operand layout, split into 2 frags
// (q-cols 0-15, 16-31). Lane l, elem jj of frag f:
//   maskval[key = kt*32 + (l&31)][q = qg*32 + f*16 + 8*(l>>5) + jj]
// Storage: o[u*1024 + l*8 + f*512 + jj], u = ((bb*64)+qg)*64 + kt.
// ---------------------------------------------------------------------------
__global__ __launch_bounds__(256)
void conv_maskfrag(const int* __restrict__ m, short* __restrict__ o)
{
    int u = blockIdx.x * 4 + (threadIdx.x >> 6);   // 0..16383
    int l = threadIdx.x & 63;
    int l31 = l & 31, h = l >> 5;
    int kt = u & 63, qg = (u >> 6) & 63, bb = u >> 12;
    int key = kt * 32 + l31;
    const int* mb = m + (size_t)bb * S * S + key;
    size_t ob = (size_t)u * 1024 + l * 8;
#pragma unroll
    for (int f = 0; f < 2; ++f) {
        bf16x8 frag;
#pragma unroll
        for (int jj = 0; jj < 8; ++jj) {
            int q = qg * 32 + f * 16 + 8 * h + jj;
            frag[jj] = mb[(size_t)q * S] != 0 ? (short)0 : (short)0xC53B;  // -2992
        }
        *(bf16x8*)(o + ob + f * 512) = frag;
    }
}

// ---------------------------------------------------------------------------
// Fused QKV GEMM, 128x128 tile, BK=64, global_load_lds + XOR swizzle.
// C[8192,3072] = x @ [Wq;Wk;Wv]^T. grid (64, 24); block 256 = 4 waves (2x2).
// Epilogue: q scaled by log2e/8 -> [B,H,S,64]; k -> [B,H,S,64]; v -> [B,H,64,S].
// ---------------------------------------------------------------------------
__global__ __launch_bounds__(256, 3)
void qkv_mfma(const short* __restrict__ xb, const short* __restrict__ wcat,
              const float* __restrict__ bq, const float* __restrict__ bk,
              const float* __restrict__ bv,
              short* __restrict__ qo, short* __restrict__ ko, short* __restrict__ vto)
{
    __shared__ short As[128 * 64];
    __shared__ short Bs[128 * 64];
    const int t = threadIdx.x, lane = t & 63;
    const int w = __builtin_amdgcn_readfirstlane(t >> 6);
    const int lr = lane & 15, lg = lane >> 4;
    const int wr = w >> 1, wc = w & 1;
    const int m0 = blockIdx.x * 128, n0 = blockIdx.y * 128;

    const int srow = t >> 3;                            // 0..31
    const int scol = ((t & 7) ^ (srow & 7)) * 8;        // pre-swizzled col group
    const short* asrc = xb   + (size_t)(m0 + srow) * 1024 + scol;
    const short* bsrc = wcat + (size_t)(n0 + srow) * 1024 + scol;
    char* aldst = (char*)As + w * 1024;                 // HW adds lane*16
    char* bldst = (char*)Bs + w * 1024;

    f32x4 z = {0.f, 0.f, 0.f, 0.f};
    f32x4 acc[4][4];
#pragma unroll
    for (int i = 0; i < 4; ++i)
#pragma unroll
        for (int jj = 0; jj < 4; ++jj) acc[i][jj] = z;

    for (int kt = 0; kt < 1024; kt += 64) {
        __syncthreads();
        GLDS16(asrc + kt,             aldst);
        GLDS16(asrc + kt + 32 * 1024, aldst + 4096);
        GLDS16(asrc + kt + 64 * 1024, aldst + 8192);
        GLDS16(asrc + kt + 96 * 1024, aldst + 12288);
        GLDS16(bsrc + kt,             bldst);
        GLDS16(bsrc + kt + 32 * 1024, bldst + 4096);
        GLDS16(bsrc + kt + 64 * 1024, bldst + 8192);
        GLDS16(bsrc + kt + 96 * 1024, bldst + 12288);
        __syncthreads();
#pragma unroll
        for (int ks = 0; ks < 2; ++ks) {
            bf16x8 af[4], bfr[4];
#pragma unroll
            for (int fi = 0; fi < 4; ++fi) {
                const int ra = wr * 64 + fi * 16 + lr;
                af[fi] = *(const bf16x8*)((const char*)As + ra * 128 +
                          ((ks * 64 + lg * 16) ^ ((ra & 7) << 4)));
                const int rb = wc * 64 + fi * 16 + lr;
                bfr[fi] = *(const bf16x8*)((const char*)Bs + rb * 128 +
                          ((ks * 64 + lg * 16) ^ ((rb & 7) << 4)));
            }
#pragma unroll
            for (int fi = 0; fi < 4; ++fi)
#pragma unroll
                for (int fj = 0; fj < 4; ++fj)
                    acc[fi][fj] = MFMA16(af[fi], bfr[fj], acc[fi][fj]);
        }
    }

    const int bb = m0 >> 11;
    const int ssb = (m0 & (S - 1)) + wr * 64 + lg * 4;
    const int mat = n0 >> 10;
    const int nbase = (n0 & 1023) + wc * 64;

    if (mat == 0) {
#pragma unroll
        for (int fj = 0; fj < 4; ++fj) {
            const int nl = nbase + fj * 16 + lr, hh = nl >> 6, hd = nl & 63;
            const float bi = bq[nl];
#pragma unroll
            for (int fi = 0; fi < 4; ++fi)
#pragma unroll
                for (int r = 0; r < 4; ++r)
                    qo[(((size_t)bb * H + hh) * S + ssb + fi * 16 + r) * 64 + hd] =
                        f2bf((acc[fi][fj][r] + bi) * QSCL);
        }
    } else if (mat == 1) {
#pragma unroll
        for (int fj = 0; fj < 4; ++fj) {
            const int nl = nbase + fj * 16 + lr, hh = nl >> 6, hd = nl & 63;
            const float bi = bk[nl];
#pragma unroll
            for (int fi = 0; fi < 4; ++fi)
#pragma unroll
                for (int r = 0; r < 4; ++r)
                    ko[(((size_t)bb * H + hh) * S + ssb + fi * 16 + r) * 64 + hd] =
                        f2bf(acc[fi][fj][r] + bi);
        }
    } else {
#pragma unroll
        for (int fj = 0; fj < 4; ++fj) {
            const int nl = nbase + fj * 16 + lr, hh = nl >> 6, hd = nl & 63;
            const float bi = bv[nl];
#pragma unroll
            for (int fi = 0; fi < 4; ++fi) {
                s16x4 pk;
#pragma unroll
                for (int r = 0; r < 4; ++r) pk[r] = f2bf(acc[fi][fj][r] + bi);
                *(s16x4*)(vto + (((size_t)bb * H + hh) * 64 + hd) * S + ssb + fi * 16) = pk;
            }
        }
    }
}

// ---------------------------------------------------------------------------
// Flash attention v5: swapped-QK 32x32 MFMA, native exp2, Lacc via ones-MFMA.
// MODE 1: mask via MFMA bias (A-frag x identity-B into QK accumulator init).
// MODE 0: mask via per-element select from column words (R8 path).
// 4 waves x 32 q = 128 q. grid 1024 (XCD-grouped).
// ---------------------------------------------------------------------------
template<int USEFRAG>
__global__ __launch_bounds__(256, 3)
void attn_mfma5(const short* __restrict__ qg, const short* __restrict__ kg,
                const short* __restrict__ vtg,
                const unsigned* __restrict__ mcol,
                const short* __restrict__ mfrag,
                short* __restrict__ hc)
{
    __shared__ short Kl[2][64 * 64];
    __shared__ short Vl[2][64 * 64];

    const int t = threadIdx.x, lane = t & 63;
    const int w = __builtin_amdgcn_readfirstlane(t >> 6);
    const int l31 = lane & 31, h = lane >> 5;

    const int id = blockIdx.x;
    const int xcd = id & 7, j = id >> 3;
    const int bh = xcd + 8 * (j >> 4);
    const int q0 = (j & 15) * 128;
    const int bb = bh >> 4, hh = bh & 15;

    const short* qb  = qg  + (size_t)bh * S * 64;
    const short* kb  = kg  + (size_t)bh * S * 64;
    const short* vtb = vtg + (size_t)bh * 64 * S;
    const int bqg = bb * 64 + (q0 >> 5) + w;
    const unsigned* mc = mcol + (size_t)bqg * 32 * 64 + lane;
    const short* mfb = mfrag + (size_t)bqg * 65536 + lane * 8;

    const int qrow = q0 + w * 32 + l31;
    bf16x8 qf[4];
#pragma unroll
    for (int ds = 0; ds < 4; ++ds)
        qf[ds] = *(const bf16x8*)(qb + (size_t)qrow * 64 + ds * 16 + 8 * h);

    // identity B fragments for the mask-bias MFMAs
    bf16x8 idB0, idB1;
#pragma unroll
    for (int jj = 0; jj < 8; ++jj) {
        idB0[jj] = (8 * h + jj == l31)      ? (short)0x3F80 : (short)0;
        idB1[jj] = (8 * h + jj + 16 == l31) ? (short)0x3F80 : (short)0;
    }

    const int sk = t >> 3;                                    // staging row 0..31
    const int soff = (((t & 7) * 16) ^ ((sk & 7) << 4)) >> 1; // pre-swizzled src elem
    const int rbyte = l31 * 128;
    const int sz = (lane & 7) << 4;

    f32x16 z16;
#pragma unroll
    for (int i = 0; i < 16; ++i) z16[i] = 0.f;
    f32x16 O0 = z16, O1 = z16, Lacc = z16;

    bf16x8 ones;
#pragma unroll
    for (int i = 0; i < 8; ++i) ones[i] = (short)0x3F80;

    auto issue_stage = [&](int kt, int buf) {
        const short* ks0 = kb + (size_t)(kt + sk) * 64 + soff;
        const short* vs0 = vtb + (size_t)sk * S + kt + soff;
        char* kB = (char*)&Kl[buf][0] + w * 1024;
        char* vB = (char*)&Vl[buf][0] + w * 1024;
        GLDS16(ks0, kB);
        GLDS16(ks0 + 32 * 64, kB + 4096);
        GLDS16(vs0, vB);
        GLDS16(vs0 + (size_t)32 * S, vB + 4096);
    };

    issue_stage(0, 0);
    __syncthreads();

    for (int tile = 0; tile < 32; ++tile) {
        const int cur = tile & 1;
        if (tile < 31) issue_stage((tile + 1) * 64, cur ^ 1);

        // ---- accumulator init: mask bias (frag path) or zero (select path)
        f32x16 s0, s1;
        unsigned mcw = 0;
        if (USEFRAG) {
            const short* mfp = mfb + tile * 2048;
            bf16x8 A0a = *(const bf16x8*)(mfp);
            bf16x8 A0b = *(const bf16x8*)(mfp + 512);
            bf16x8 A1a = *(const bf16x8*)(mfp + 1024);
            bf16x8 A1b = *(const bf16x8*)(mfp + 1536);
            s0 = MFMA32(A0a, idB0, z16);
            s0 = MFMA32(A0b, idB1, s0);
            s1 = MFMA32(A1a, idB0, z16);
            s1 = MFMA32(A1b, idB1, s1);
        } else {
            s0 = z16; s1 = z16;
            mcw = mc[tile * 64];
        }

        // ---- QK^T (swapped): lane owns q-row l31
        const char* Kb = (const char*)&Kl[cur][0];
#pragma unroll
        for (int ds = 0; ds < 4; ++ds) {
            const int off = ((ds * 32 + h * 16) ^ sz);
            bf16x8 a0 = *(const bf16x8*)(Kb + rbyte + off);
            bf16x8 a1 = *(const bf16x8*)(Kb + 4096 + rbyte + off);
            s0 = MFMA32(a0, qf[ds], s0);
            s1 = MFMA32(a1, qf[ds], s1);
        }

        // ---- p = 2^s (masked s already ~ -2992) ; pack ; PV + li accumulate
        const char* Vb = (const char*)&Vl[cur][0];
#pragma unroll
        for (int ks = 0; ks < 4; ++ks) {
            const int rb = (ks < 2) ? ks * 8 : (ks - 2) * 8;
            const int wb = (ks < 2) ? rb : 16 + rb;
            float pv[8];
#pragma unroll
            for (int jj = 0; jj < 8; ++jj) {
                float sv = (ks < 2) ? s0[rb + jj] : s1[rb + jj];
                if (!USEFRAG)
                    sv = (mcw & (1u << (wb + jj))) ? sv : -INFINITY;
                pv[jj] = EXP2(sv);        // 2^-inf / 2^-2990 == 0
            }
            int w0a, w1a, w0b, w1b;
            asm("v_cvt_pk_bf16_f32 %0, %1, %2" : "=v"(w0a) : "v"(pv[0]), "v"(pv[1]));
            asm("v_cvt_pk_bf16_f32 %0, %1, %2" : "=v"(w1a) : "v"(pv[2]), "v"(pv[3]));
            asm("v_cvt_pk_bf16_f32 %0, %1, %2" : "=v"(w0b) : "v"(pv[4]), "v"(pv[5]));
            asm("v_cvt_pk_bf16_f32 %0, %1, %2" : "=v"(w1b) : "v"(pv[6]), "v"(pv[7]));
            asm("v_permlane32_swap_b32 %0, %1" : "+v"(w0a), "+v"(w0b));
            asm("v_permlane32_swap_b32 %0, %1" : "+v"(w1a), "+v"(w1b));
            union { int i[4]; bf16x8 v; } pf;
            pf.i[0] = w0a; pf.i[1] = w1a; pf.i[2] = w0b; pf.i[3] = w1b;

            const int koff = ((ks * 32 + h * 16) ^ sz);
            bf16x8 v0 = *(const bf16x8*)(Vb + rbyte + koff);
            bf16x8 v1 = *(const bf16x8*)(Vb + 4096 + rbyte + koff);
            O0 = MFMA32(pf.v, v0, O0);
            O1 = MFMA32(pf.v, v1, O1);
            Lacc = MFMA32(pf.v, ones, Lacc);
        }
        __syncthreads();
    }

    // ---- epilogue: Lacc[r] is this lane's row-sum; normalize and store
    const size_t outb = (size_t)bb * S * D + (size_t)hh * 64;
#pragma unroll
    for (int r = 0; r < 16; ++r) {
        const float inv = 1.f / Lacc[r];
        const int row = q0 + w * 32 + (r & 3) + 8 * (r >> 2) + 4 * h;
        hc[outb + (size_t)row * D + l31]      = f2bf(O0[r] * inv);
        hc[outb + (size_t)row * D + 32 + l31] = f2bf(O1[r] * inv);
    }
}

// ---------------------------------------------------------------------------
// Output projection, 128x128 tile, fp32 out. grid (64, 8); block 256.
// ---------------------------------------------------------------------------
__global__ __launch_bounds__(256, 3)
void proj_mfma(const short* __restrict__ hb, const short* __restrict__ wfb,
               const float* __restrict__ bfp, float* __restrict__ out)
{
    __shared__ short As[128 * 64];
    __shared__ short Bs[128 * 64];
    const int t = threadIdx.x, lane = t & 63;
    const int w = __builtin_amdgcn_readfirstlane(t >> 6);
    const int lr = lane & 15, lg = lane >> 4;
    const int wr = w >> 1, wc = w & 1;
    const int m0 = blockIdx.x * 128, n0 = blockIdx.y * 128;

    const int srow = t >> 3;
    const int scol = ((t & 7) ^ (srow & 7)) * 8;
    const short* asrc = hb  + (size_t)(m0 + srow) * 1024 + scol;
    const short* bsrc = wfb + (size_t)(n0 + srow) * 1024 + scol;
    char* aldst = (char*)As + w * 1024;
    char* bldst = (char*)Bs + w * 1024;

    f32x4 z = {0.f, 0.f, 0.f, 0.f};
    f32x4 acc[4][4];
#pragma unroll
    for (int i = 0; i < 4; ++i)
#pragma unroll
        for (int jj = 0; jj < 4; ++jj) acc[i][jj] = z;

    for (int kt = 0; kt < 1024; kt += 64) {
        __syncthreads();
        GLDS16(asrc + kt,             aldst);
        GLDS16(asrc + kt + 32 * 1024, aldst + 4096);
        GLDS16(asrc + kt + 64 * 1024, aldst + 8192);
        GLDS16(asrc + kt + 96 * 1024, aldst + 12288);
        GLDS16(bsrc + kt,             bldst);
        GLDS16(bsrc + kt + 32 * 1024, bldst + 4096);
        GLDS16(bsrc + kt + 64 * 1024, bldst + 8192);
        GLDS16(bsrc + kt + 96 * 1024, bldst + 12288);
        __syncthreads();
#pragma unroll
        for (int ks = 0; ks < 2; ++ks) {
            bf16x8 af[4], bfr[4];
#pragma unroll
            for (int fi = 0; fi < 4; ++fi) {
                const int ra = wr * 64 + fi * 16 + lr;
                af[fi] = *(const bf16x8*)((const char*)As + ra * 128 +
                          ((ks * 64 + lg * 16) ^ ((ra & 7) << 4)));
                const int rb = wc * 64 + fi * 16 + lr;
                bfr[fi] = *(const bf16x8*)((const char*)Bs + rb * 128 +
                          ((ks * 64 + lg * 16) ^ ((rb & 7) << 4)));
            }
#pragma unroll
            for (int fi = 0; fi < 4; ++fi)
#pragma unroll
                for (int fj = 0; fj < 4; ++fj)
                    acc[fi][fj] = MFMA16(af[fi], bfr[fj], acc[fi][fj]);
        }
    }

#pragma unroll
    for (int fj = 0; fj < 4; ++fj) {
        const int nl = n0 + wc * 64 + fj * 16 + lr;
        const float bi = bfp[nl];
#pragma unroll
        for (int fi = 0; fi < 4; ++fi)
#pragma unroll
            for (int r = 0; r < 4; ++r)
                out[(size_t)(m0 + wr * 64 + fi * 16 + lg * 4 + r) * 1024 + nl] =
                    acc[fi][fj][r] + bi;
    }
}

// ---------------------------------------------------------------------------
extern "C" void kernel_launch(void* const* d_in, const int* in_sizes, int n_in,
                              void* d_out, int out_size, void* d_ws, size_t ws_size,
                              hipStream_t stream)
{
    const float* x  = (const float*)d_in[0];
    const int* mask = (const int*)d_in[1];
    const float* Wq = (const float*)d_in[2];
    const float* bq = (const float*)d_in[3];
    const float* Wk = (const float*)d_in[4];
    const float* bk = (const float*)d_in[5];
    const float* Wv = (const float*)d_in[6];
    const float* bv = (const float*)d_in[7];
    const float* Wf = (const float*)d_in[8];
    const float* bf = (const float*)d_in[9];
    float* out = (float*)d_out;

    char* p = (char*)d_ws;
    short* xb  = (short*)p; p += 16777216;                       // x bf16
    short* wqb = (short*)p; p += 2097152;                        // [Wq;Wk;Wv;Wf] bf16
    short* wkb = (short*)p; p += 2097152;
    short* wvb = (short*)p; p += 2097152;
    short* wfb = (short*)p; p += 2097152;
    short* qb  = (short*)p; p += 16777216;                       // [B,H,S,64]
    short* kb  = (short*)p; p += 16777216;                       // [B,H,S,64]
    short* vtb = (short*)p; p += 16777216;                       // [B,H,64,S]
    short* hcb = (short*)p; p += 16777216;                       // [B,S,D]
    unsigned* mcol = (unsigned*)p; p += 2097152;                 // mask column words
    short* mfrag = (short*)p; p += 33554432;                     // mask bias A-frags
    const size_t need_frag = (size_t)(p - (char*)d_ws);

    const bool usefrag = ws_size >= need_frag;

    conv_pack<<<12288, 256, 0, stream>>>(x, Wq, Wk, Wv, Wf, xb, wqb, wkb, wvb, wfb);
    qkv_mfma<<<dim3(64, 24), 256, 0, stream>>>(xb, wqb, bq, bk, bv, qb, kb, vtb);
    if (usefrag) {
        conv_maskfrag<<<4096, 256, 0, stream>>>(mask, mfrag);
        attn_mfma5<1><<<1024, 256, 0, stream>>>(qb, kb, vtb, mcol, mfrag, hcb);
    } else {
        conv_maskcol<<<2048, 256, 0, stream>>>(mask, mcol);
        attn_mfma5<0><<<1024, 256, 0, stream>>>(qb, kb, vtb, mcol, mfrag, hcb);
    }
    proj_mfma<<<dim3(64, 8), 256, 0, stream>>>(hcb, wfb, bf, out);
}

// Round 12
// 213.602 us; speedup vs baseline: 10.6837x; 1.0231x over previous
//
#include <hip/hip_runtime.h>
#include <math.h>

constexpr int S = 2048, D = 1024, H = 16;
constexpr float QSCL = 0.18033688011112042f;   // log2(e) / sqrt(64)

typedef __attribute__((ext_vector_type(8))) short bf16x8;
typedef __attribute__((ext_vector_type(4))) short s16x4;
typedef __attribute__((ext_vector_type(4))) float f32x4;
typedef __attribute__((ext_vector_type(16))) float f32x16;

#define MFMA16(a,b,c) __builtin_amdgcn_mfma_f32_16x16x32_bf16(a,b,c,0,0,0)
#define MFMA32(a,b,c) __builtin_amdgcn_mfma_f32_32x32x16_bf16(a,b,c,0,0,0)

#if __has_builtin(__builtin_amdgcn_exp2f)
#define EXP2(x) __builtin_amdgcn_exp2f(x)
#else
#define EXP2(x) exp2f(x)
#endif

#define GLDS16(g, l) __builtin_amdgcn_global_load_lds( \
    (const __attribute__((address_space(1))) unsigned*)(const void*)(g), \
    (__attribute__((address_space(3))) unsigned*)(void*)(l), 16, 0, 0)

__device__ inline short f2bf(float f) {
    union { float f; unsigned u; } c; c.f = f;
    unsigned u = c.u + 0x7fffu + ((c.u >> 16) & 1u);
    return (short)(u >> 16);
}

// ---------------------------------------------------------------------------
// Convert x and the 4 weight matrices to bf16 (RNE). wq..wf land contiguous.
// ---------------------------------------------------------------------------
__global__ __launch_bounds__(256)
void conv_pack(const float* __restrict__ x,  const float* __restrict__ wq,
               const float* __restrict__ wk, const float* __restrict__ wv,
               const float* __restrict__ wf,
               short* __restrict__ xb,  short* __restrict__ wqb,
               short* __restrict__ wkb, short* __restrict__ wvb,
               short* __restrict__ wfb)
{
    int i = blockIdx.x * 256 + threadIdx.x;
    const float* s; short* d; int o;
    if (i < 2097152) { s = x; d = xb; o = i; }
    else {
        int j = i - 2097152; int wsel = j >> 18; o = j & 262143;
        s = wsel == 0 ? wq : wsel == 1 ? wk : wsel == 2 ? wv : wf;
        d = wsel == 0 ? wqb : wsel == 1 ? wkb : wsel == 2 ? wvb : wfb;
    }
    float4 v = ((const float4*)s)[o];
    s16x4 r; r.x = f2bf(v.x); r.y = f2bf(v.y); r.z = f2bf(v.z); r.w = f2bf(v.w);
    ((s16x4*)d)[o] = r;
}

// ---------------------------------------------------------------------------
// Per-lane mask column words (fallback path). Bit r of word(lane) =
// mask[bb][grp*32+(lane&31)][tile*64 + (r&3)+8*((r>>2)&3)+32*(r>>4)+4*(lane>>5)]
// ---------------------------------------------------------------------------
__global__ __launch_bounds__(256)
void conv_maskcol(const int* __restrict__ m, unsigned* __restrict__ o)
{
    int gid = blockIdx.x * 256 + threadIdx.x;      // 2048 blocks -> 524288
    int lane = gid & 63;
    int tile = (gid >> 6) & 31;
    int grp  = (gid >> 11) & 63;
    int bb   = gid >> 17;
    int qrow = grp * 32 + (lane & 31);
    int h = lane >> 5;
    const int* base = m + (size_t)bb * S * S + (size_t)qrow * S + tile * 64 + 4 * h;
    unsigned wbits = 0;
#pragma unroll
    for (int a = 0; a < 8; ++a) {
        int4 v = *(const int4*)(base + 8 * (a & 3) + 32 * (a >> 2));
        wbits |= (v.x != 0 ? 1u : 0u) << (4 * a);
        wbits |= (v.y != 0 ? 1u : 0u) << (4 * a + 1);
        wbits |= (v.z != 0 ? 1u : 0u) << (4 * a + 2);
        wbits |= (v.w != 0 ? 1u : 0u) << (4 * a + 3);
    }
    o[gid] = wbits;
}

// ---------------------------------------------------------------------------
// Mask bias A-fragments (frag path): per (b, qgrp32, kblk32) a 32x32 block of
// bf16 {0 keep, -2992 masked} in MFMA32 A-operand layout, split into 2 frags.
// Lane l, elem jj of frag f: maskval[key = kt*32+(l&31)][q = qg*32+f*16+8*(l>>5)+jj]
// ---------------------------------------------------------------------------
__global__ __launch_bounds__(256)
void conv_maskfrag(const int* __restrict__ m, short* __restrict__ o)
{
    int u = blockIdx.x * 4 + (threadIdx.x >> 6);   // 0..16383
    int l = threadIdx.x & 63;
    int l31 = l & 31, h = l >> 5;
    int kt = u & 63, qg = (u >> 6) & 63, bb = u >> 12;
    int key = kt * 32 + l31;
    const int* mb = m + (size_t)bb * S * S + key;
    size_t ob = (size_t)u * 1024 + l * 8;
#pragma unroll
    for (int f = 0; f < 2; ++f) {
        bf16x8 frag;
#pragma unroll
        for (int jj = 0; jj < 8; ++jj) {
            int q = qg * 32 + f * 16 + 8 * h + jj;
            frag[jj] = mb[(size_t)q * S] != 0 ? (short)0 : (short)0xC53B;  // -2992
        }
        *(bf16x8*)(o + ob + f * 512) = frag;
    }
}

// ---------------------------------------------------------------------------
// Fused QKV GEMM, 128x128 tile, BK=64, global_load_lds + XOR swizzle.
// C[8192,3072] = x @ [Wq;Wk;Wv]^T. grid (64, 24); block 256 = 4 waves (2x2).
// Epilogue: q scaled by log2e/8 -> [B,H,S,64]; k -> [B,H,S,64]; v -> [B,H,64,S].
// ---------------------------------------------------------------------------
__global__ __launch_bounds__(256, 3)
void qkv_mfma(const short* __restrict__ xb, const short* __restrict__ wcat,
              const float* __restrict__ bq, const float* __restrict__ bk,
              const float* __restrict__ bv,
              short* __restrict__ qo, short* __restrict__ ko, short* __restrict__ vto)
{
    __shared__ short As[128 * 64];
    __shared__ short Bs[128 * 64];
    const int t = threadIdx.x, lane = t & 63;
    const int w = __builtin_amdgcn_readfirstlane(t >> 6);
    const int lr = lane & 15, lg = lane >> 4;
    const int wr = w >> 1, wc = w & 1;
    const int m0 = blockIdx.x * 128, n0 = blockIdx.y * 128;

    const int srow = t >> 3;                            // 0..31
    const int scol = ((t & 7) ^ (srow & 7)) * 8;        // pre-swizzled col group
    const short* asrc = xb   + (size_t)(m0 + srow) * 1024 + scol;
    const short* bsrc = wcat + (size_t)(n0 + srow) * 1024 + scol;
    char* aldst = (char*)As + w * 1024;                 // HW adds lane*16
    char* bldst = (char*)Bs + w * 1024;

    f32x4 z = {0.f, 0.f, 0.f, 0.f};
    f32x4 acc[4][4];
#pragma unroll
    for (int i = 0; i < 4; ++i)
#pragma unroll
        for (int jj = 0; jj < 4; ++jj) acc[i][jj] = z;

    for (int kt = 0; kt < 1024; kt += 64) {
        __syncthreads();
        GLDS16(asrc + kt,             aldst);
        GLDS16(asrc + kt + 32 * 1024, aldst + 4096);
        GLDS16(asrc + kt + 64 * 1024, aldst + 8192);
        GLDS16(asrc + kt + 96 * 1024, aldst + 12288);
        GLDS16(bsrc + kt,             bldst);
        GLDS16(bsrc + kt + 32 * 1024, bldst + 4096);
        GLDS16(bsrc + kt + 64 * 1024, bldst + 8192);
        GLDS16(bsrc + kt + 96 * 1024, bldst + 12288);
        __syncthreads();
#pragma unroll
        for (int ks = 0; ks < 2; ++ks) {
            bf16x8 af[4], bfr[4];
#pragma unroll
            for (int fi = 0; fi < 4; ++fi) {
                const int ra = wr * 64 + fi * 16 + lr;
                af[fi] = *(const bf16x8*)((const char*)As + ra * 128 +
                          ((ks * 64 + lg * 16) ^ ((ra & 7) << 4)));
                const int rb = wc * 64 + fi * 16 + lr;
                bfr[fi] = *(const bf16x8*)((const char*)Bs + rb * 128 +
                          ((ks * 64 + lg * 16) ^ ((rb & 7) << 4)));
            }
#pragma unroll
            for (int fi = 0; fi < 4; ++fi)
#pragma unroll
                for (int fj = 0; fj < 4; ++fj)
                    acc[fi][fj] = MFMA16(af[fi], bfr[fj], acc[fi][fj]);
        }
    }

    const int bb = m0 >> 11;
    const int ssb = (m0 & (S - 1)) + wr * 64 + lg * 4;
    const int mat = n0 >> 10;
    const int nbase = (n0 & 1023) + wc * 64;

    if (mat == 0) {
#pragma unroll
        for (int fj = 0; fj < 4; ++fj) {
            const int nl = nbase + fj * 16 + lr, hh = nl >> 6, hd = nl & 63;
            const float bi = bq[nl];
#pragma unroll
            for (int fi = 0; fi < 4; ++fi)
#pragma unroll
                for (int r = 0; r < 4; ++r)
                    qo[(((size_t)bb * H + hh) * S + ssb + fi * 16 + r) * 64 + hd] =
                        f2bf((acc[fi][fj][r] + bi) * QSCL);
        }
    } else if (mat == 1) {
#pragma unroll
        for (int fj = 0; fj < 4; ++fj) {
            const int nl = nbase + fj * 16 + lr, hh = nl >> 6, hd = nl & 63;
            const float bi = bk[nl];
#pragma unroll
            for (int fi = 0; fi < 4; ++fi)
#pragma unroll
                for (int r = 0; r < 4; ++r)
                    ko[(((size_t)bb * H + hh) * S + ssb + fi * 16 + r) * 64 + hd] =
                        f2bf(acc[fi][fj][r] + bi);
        }
    } else {
#pragma unroll
        for (int fj = 0; fj < 4; ++fj) {
            const int nl = nbase + fj * 16 + lr, hh = nl >> 6, hd = nl & 63;
            const float bi = bv[nl];
#pragma unroll
            for (int fi = 0; fi < 4; ++fi) {
                s16x4 pk;
#pragma unroll
                for (int r = 0; r < 4; ++r) pk[r] = f2bf(acc[fi][fj][r] + bi);
                *(s16x4*)(vto + (((size_t)bb * H + hh) * 64 + hd) * S + ssb + fi * 16) = pk;
            }
        }
    }
}

// ---------------------------------------------------------------------------
// Flash attention v7: swapped-QK 32x32 MFMA, native exp2, Lacc via ones-MFMA,
// mask-bias fragments register-prefetched one tile ahead. Occupancy kept at 3
// blocks/CU (R10's forced 4 caused register-pressure rematerialization of the
// cross-lane asm -> corruption). All cross-lane/pack asm is volatile.
// 4 waves x 32 q = 128 q. grid 1024 (XCD-grouped).
// ---------------------------------------------------------------------------
template<int USEFRAG>
__global__ __launch_bounds__(256, 3)
void attn_mfma7(const short* __restrict__ qg, const short* __restrict__ kg,
                const short* __restrict__ vtg,
                const unsigned* __restrict__ mcol,
                const short* __restrict__ mfrag,
                short* __restrict__ hc)
{
    __shared__ short Kl[2][64 * 64];
    __shared__ short Vl[2][64 * 64];

    const int t = threadIdx.x, lane = t & 63;
    const int w = __builtin_amdgcn_readfirstlane(t >> 6);
    const int l31 = lane & 31, h = lane >> 5;

    const int id = blockIdx.x;
    const int xcd = id & 7, j = id >> 3;
    const int bh = xcd + 8 * (j >> 4);
    const int q0 = (j & 15) * 128;
    const int bb = bh >> 4, hh = bh & 15;

    const short* qb  = qg  + (size_t)bh * S * 64;
    const short* kb  = kg  + (size_t)bh * S * 64;
    const short* vtb = vtg + (size_t)bh * 64 * S;
    const int bqg = bb * 64 + (q0 >> 5) + w;
    const unsigned* mc = mcol + (size_t)bqg * 32 * 64 + lane;
    const short* mfb = mfrag + (size_t)bqg * 65536 + lane * 8;

    const int qrow = q0 + w * 32 + l31;
    bf16x8 qf[4];
#pragma unroll
    for (int ds = 0; ds < 4; ++ds)
        qf[ds] = *(const bf16x8*)(qb + (size_t)qrow * 64 + ds * 16 + 8 * h);

    // identity B fragments for the mask-bias MFMAs
    bf16x8 idB0, idB1;
#pragma unroll
    for (int jj = 0; jj < 8; ++jj) {
        idB0[jj] = (8 * h + jj == l31)      ? (short)0x3F80 : (short)0;
        idB1[jj] = (8 * h + jj + 16 == l31) ? (short)0x3F80 : (short)0;
    }

    const int sk = t >> 3;                                    // staging row 0..31
    const int soff = (((t & 7) * 16) ^ ((sk & 7) << 4)) >> 1; // pre-swizzled src elem
    const int rbyte = l31 * 128;
    const int sz = (lane & 7) << 4;

    f32x16 z16;
#pragma unroll
    for (int i = 0; i < 16; ++i) z16[i] = 0.f;
    f32x16 O0 = z16, O1 = z16, Lacc = z16;

    bf16x8 ones;
#pragma unroll
    for (int i = 0; i < 8; ++i) ones[i] = (short)0x3F80;

    auto issue_stage = [&](int kt, int buf) {
        const short* ks0 = kb + (size_t)(kt + sk) * 64 + soff;
        const short* vs0 = vtb + (size_t)sk * S + kt + soff;
        char* kB = (char*)&Kl[buf][0] + w * 1024;
        char* vB = (char*)&Vl[buf][0] + w * 1024;
        GLDS16(ks0, kB);
        GLDS16(ks0 + 32 * 64, kB + 4096);
        GLDS16(vs0, vB);
        GLDS16(vs0 + (size_t)32 * S, vB + 4096);
    };

    // tile-0 prefetch of mask data into registers
    bf16x8 fr0, fr1, fr2, fr3;
    unsigned mcw = 0;
    if (USEFRAG) {
        fr0 = *(const bf16x8*)(mfb);
        fr1 = *(const bf16x8*)(mfb + 512);
        fr2 = *(const bf16x8*)(mfb + 1024);
        fr3 = *(const bf16x8*)(mfb + 1536);
    } else {
        mcw = mc[0];
    }

    issue_stage(0, 0);
    __syncthreads();

    for (int tile = 0; tile < 32; ++tile) {
        const int cur = tile & 1;
        // prefetch next tile: K/V -> LDS, mask frags/word -> registers
        bf16x8 nf0, nf1, nf2, nf3;
        unsigned mcn = 0;
        if (tile < 31) {
            issue_stage((tile + 1) * 64, cur ^ 1);
            if (USEFRAG) {
                const short* mfn = mfb + (tile + 1) * 2048;
                nf0 = *(const bf16x8*)(mfn);
                nf1 = *(const bf16x8*)(mfn + 512);
                nf2 = *(const bf16x8*)(mfn + 1024);
                nf3 = *(const bf16x8*)(mfn + 1536);
            } else {
                mcn = mc[(tile + 1) * 64];
            }
        }

        // ---- accumulator init: mask bias (frag path) or zero (select path)
        f32x16 s0, s1;
        if (USEFRAG) {
            s0 = MFMA32(fr0, idB0, z16);
            s0 = MFMA32(fr1, idB1, s0);
            s1 = MFMA32(fr2, idB0, z16);
            s1 = MFMA32(fr3, idB1, s1);
        } else {
            s0 = z16; s1 = z16;
        }

        // ---- QK^T (swapped): lane owns q-row l31
        const char* Kb = (const char*)&Kl[cur][0];
#pragma unroll
        for (int ds = 0; ds < 4; ++ds) {
            const int off = ((ds * 32 + h * 16) ^ sz);
            bf16x8 a0 = *(const bf16x8*)(Kb + rbyte + off);
            bf16x8 a1 = *(const bf16x8*)(Kb + 4096 + rbyte + off);
            s0 = MFMA32(a0, qf[ds], s0);
            s1 = MFMA32(a1, qf[ds], s1);
        }

        // ---- p = 2^s (masked s ~ -2992 -> 0) ; pack ; PV + li accumulate
        const char* Vb = (const char*)&Vl[cur][0];
#pragma unroll
        for (int ks = 0; ks < 4; ++ks) {
            const int rb = (ks < 2) ? ks * 8 : (ks - 2) * 8;
            const int wb = (ks < 2) ? rb : 16 + rb;
            float pv[8];
#pragma unroll
            for (int jj = 0; jj < 8; ++jj) {
                float sv = (ks < 2) ? s0[rb + jj] : s1[rb + jj];
                if (!USEFRAG)
                    sv = (mcw & (1u << (wb + jj))) ? sv : -INFINITY;
                pv[jj] = EXP2(sv);
            }
            int w0a, w1a, w0b, w1b;
            asm volatile("v_cvt_pk_bf16_f32 %0, %1, %2" : "=v"(w0a) : "v"(pv[0]), "v"(pv[1]));
            asm volatile("v_cvt_pk_bf16_f32 %0, %1, %2" : "=v"(w1a) : "v"(pv[2]), "v"(pv[3]));
            asm volatile("v_cvt_pk_bf16_f32 %0, %1, %2" : "=v"(w0b) : "v"(pv[4]), "v"(pv[5]));
            asm volatile("v_cvt_pk_bf16_f32 %0, %1, %2" : "=v"(w1b) : "v"(pv[6]), "v"(pv[7]));
            asm volatile("v_permlane32_swap_b32 %0, %1" : "+v"(w0a), "+v"(w0b));
            asm volatile("v_permlane32_swap_b32 %0, %1" : "+v"(w1a), "+v"(w1b));
            union { int i[4]; bf16x8 v; } pf;
            pf.i[0] = w0a; pf.i[1] = w1a; pf.i[2] = w0b; pf.i[3] = w1b;

            const int koff = ((ks * 32 + h * 16) ^ sz);
            bf16x8 v0 = *(const bf16x8*)(Vb + rbyte + koff);
            bf16x8 v1 = *(const bf16x8*)(Vb + 4096 + rbyte + koff);
            O0 = MFMA32(pf.v, v0, O0);
            O1 = MFMA32(pf.v, v1, O1);
            Lacc = MFMA32(pf.v, ones, Lacc);
        }

        if (tile < 31) {
            if (USEFRAG) { fr0 = nf0; fr1 = nf1; fr2 = nf2; fr3 = nf3; }
            else mcw = mcn;
        }
        __syncthreads();
    }

    // ---- epilogue: Lacc[r] is this lane's row-sum; normalize and store
    const size_t outb = (size_t)bb * S * D + (size_t)hh * 64;
#pragma unroll
    for (int r = 0; r < 16; ++r) {
        const float inv = 1.f / Lacc[r];
        const int row = q0 + w * 32 + (r & 3) + 8 * (r >> 2) + 4 * h;
        hc[outb + (size_t)row * D + l31]      = f2bf(O0[r] * inv);
        hc[outb + (size_t)row * D + 32 + l31] = f2bf(O1[r] * inv);
    }
}

// ---------------------------------------------------------------------------
// Output projection, 128x128 tile, fp32 out. grid (64, 8); block 256.
// ---------------------------------------------------------------------------
__global__ __launch_bounds__(256, 3)
void proj_mfma(const short* __restrict__ hb, const short* __restrict__ wfb,
               const float* __restrict__ bfp, float* __restrict__ out)
{
    __shared__ short As[128 * 64];
    __shared__ short Bs[128 * 64];
    const int t = threadIdx.x, lane = t & 63;
    const int w = __builtin_amdgcn_readfirstlane(t >> 6);
    const int lr = lane & 15, lg = lane >> 4;
    const int wr = w >> 1, wc = w & 1;
    const int m0 = blockIdx.x * 128, n0 = blockIdx.y * 128;

    const int srow = t >> 3;
    const int scol = ((t & 7) ^ (srow & 7)) * 8;
    const short* asrc = hb  + (size_t)(m0 + srow) * 1024 + scol;
    const short* bsrc = wfb + (size_t)(n0 + srow) * 1024 + scol;
    char* aldst = (char*)As + w * 1024;
    char* bldst = (char*)Bs + w * 1024;

    f32x4 z = {0.f, 0.f, 0.f, 0.f};
    f32x4 acc[4][4];
#pragma unroll
    for (int i = 0; i < 4; ++i)
#pragma unroll
        for (int jj = 0; jj < 4; ++jj) acc[i][jj] = z;

    for (int kt = 0; kt < 1024; kt += 64) {
        __syncthreads();
        GLDS16(asrc + kt,             aldst);
        GLDS16(asrc + kt + 32 * 1024, aldst + 4096);
        GLDS16(asrc + kt + 64 * 1024, aldst + 8192);
        GLDS16(asrc + kt + 96 * 1024, aldst + 12288);
        GLDS16(bsrc + kt,             bldst);
        GLDS16(bsrc + kt + 32 * 1024, bldst + 4096);
        GLDS16(bsrc + kt + 64 * 1024, bldst + 8192);
        GLDS16(bsrc + kt + 96 * 1024, bldst + 12288);
        __syncthreads();
#pragma unroll
        for (int ks = 0; ks < 2; ++ks) {
            bf16x8 af[4], bfr[4];
#pragma unroll
            for (int fi = 0; fi < 4; ++fi) {
                const int ra = wr * 64 + fi * 16 + lr;
                af[fi] = *(const bf16x8*)((const char*)As + ra * 128 +
                          ((ks * 64 + lg * 16) ^ ((ra & 7) << 4)));
                const int rb = wc * 64 + fi * 16 + lr;
                bfr[fi] = *(const bf16x8*)((const char*)Bs + rb * 128 +
                          ((ks * 64 + lg * 16) ^ ((rb & 7) << 4)));
            }
#pragma unroll
            for (int fi = 0; fi < 4; ++fi)
#pragma unroll
                for (int fj = 0; fj < 4; ++fj)
                    acc[fi][fj] = MFMA16(af[fi], bfr[fj], acc[fi][fj]);
        }
    }

#pragma unroll
    for (int fj = 0; fj < 4; ++fj) {
        const int nl = n0 + wc * 64 + fj * 16 + lr;
        const float bi = bfp[nl];
#pragma unroll
        for (int fi = 0; fi < 4; ++fi)
#pragma unroll
            for (int r = 0; r < 4; ++r)
                out[(size_t)(m0 + wr * 64 + fi * 16 + lg * 4 + r) * 1024 + nl] =
                    acc[fi][fj][r] + bi;
    }
}

// ---------------------------------------------------------------------------
extern "C" void kernel_launch(void* const* d_in, const int* in_sizes, int n_in,
                              void* d_out, int out_size, void* d_ws, size_t ws_size,
                              hipStream_t stream)
{
    const float* x  = (const float*)d_in[0];
    const int* mask = (const int*)d_in[1];
    const float* Wq = (const float*)d_in[2];
    const float* bq = (const float*)d_in[3];
    const float* Wk = (const float*)d_in[4];
    const float* bk = (const float*)d_in[5];
    const float* Wv = (const float*)d_in[6];
    const float* bv = (const float*)d_in[7];
    const float* Wf = (const float*)d_in[8];
    const float* bf = (const float*)d_in[9];
    float* out = (float*)d_out;

    char* p = (char*)d_ws;
    short* xb  = (short*)p; p += 16777216;                       // x bf16
    short* wqb = (short*)p; p += 2097152;                        // [Wq;Wk;Wv;Wf] bf16
    short* wkb = (short*)p; p += 2097152;
    short* wvb = (short*)p; p += 2097152;
    short* wfb = (short*)p; p += 2097152;
    short* qb  = (short*)p; p += 16777216;                       // [B,H,S,64]
    short* kb  = (short*)p; p += 16777216;                       // [B,H,S,64]
    short* vtb = (short*)p; p += 16777216;                       // [B,H,64,S]
    short* hcb = (short*)p; p += 16777216;                       // [B,S,D]
    unsigned* mcol = (unsigned*)p; p += 2097152;                 // mask column words
    short* mfrag = (short*)p; p += 33554432;                     // mask bias A-frags
    const size_t need_frag = (size_t)(p - (char*)d_ws);

    const bool usefrag = ws_size >= need_frag;

    conv_pack<<<12288, 256, 0, stream>>>(x, Wq, Wk, Wv, Wf, xb, wqb, wkb, wvb, wfb);
    qkv_mfma<<<dim3(64, 24), 256, 0, stream>>>(xb, wqb, bq, bk, bv, qb, kb, vtb);
    if (usefrag) {
        conv_maskfrag<<<4096, 256, 0, stream>>>(mask, mfrag);
        attn_mfma7<1><<<1024, 256, 0, stream>>>(qb, kb, vtb, mcol, mfrag, hcb);
    } else {
        conv_maskcol<<<2048, 256, 0, stream>>>(mask, mcol);
        attn_mfma7<0><<<1024, 256, 0, stream>>>(qb, kb, vtb, mcol, mfrag, hcb);
    }
    proj_mfma<<<dim3(64, 8), 256, 0, stream>>>(hcb, wfb, bf, out);
}

// Round 15
// 195.025 us; speedup vs baseline: 11.7014x; 1.0953x over previous
//
#include <hip/hip_runtime.h>
#include <math.h>

constexpr int S = 2048, D = 1024, H = 16;
constexpr float QSCL = 0.18033688011112042f;   // log2(e) / sqrt(64)

typedef __attribute__((ext_vector_type(8))) short bf16x8;
typedef __attribute__((ext_vector_type(4))) short s16x4;
typedef __attribute__((ext_vector_type(4))) float f32x4;
typedef __attribute__((ext_vector_type(16))) float f32x16;

#define MFMA16(a,b,c) __builtin_amdgcn_mfma_f32_16x16x32_bf16(a,b,c,0,0,0)
#define MFMA32(a,b,c) __builtin_amdgcn_mfma_f32_32x32x16_bf16(a,b,c,0,0,0)

#if __has_builtin(__builtin_amdgcn_exp2f)
#define EXP2(x) __builtin_amdgcn_exp2f(x)
#else
#define EXP2(x) exp2f(x)
#endif

#define GLDS16(g, l) __builtin_amdgcn_global_load_lds( \
    (const __attribute__((address_space(1))) unsigned*)(const void*)(g), \
    (__attribute__((address_space(3))) unsigned*)(void*)(l), 16, 0, 0)

__device__ inline short f2bf(float f) {
    union { float f; unsigned u; } c; c.f = f;
    unsigned u = c.u + 0x7fffu + ((c.u >> 16) & 1u);
    return (short)(u >> 16);
}

// ---------------------------------------------------------------------------
// Convert x and the 4 weight matrices to bf16 (RNE). wq..wf land contiguous.
// ---------------------------------------------------------------------------
__global__ __launch_bounds__(256)
void conv_pack(const float* __restrict__ x,  const float* __restrict__ wq,
               const float* __restrict__ wk, const float* __restrict__ wv,
               const float* __restrict__ wf,
               short* __restrict__ xb,  short* __restrict__ wqb,
               short* __restrict__ wkb, short* __restrict__ wvb,
               short* __restrict__ wfb)
{
    int i = blockIdx.x * 256 + threadIdx.x;
    const float* s; short* d; int o;
    if (i < 2097152) { s = x; d = xb; o = i; }
    else {
        int j = i - 2097152; int wsel = j >> 18; o = j & 262143;
        s = wsel == 0 ? wq : wsel == 1 ? wk : wsel == 2 ? wv : wf;
        d = wsel == 0 ? wqb : wsel == 1 ? wkb : wsel == 2 ? wvb : wfb;
    }
    float4 v = ((const float4*)s)[o];
    s16x4 r; r.x = f2bf(v.x); r.y = f2bf(v.y); r.z = f2bf(v.z); r.w = f2bf(v.w);
    ((s16x4*)d)[o] = r;
}

// ---------------------------------------------------------------------------
// Per-lane mask column words. Bit r of word(lane) =
// mask[bb][grp*32+(lane&31)][tile*64 + (r&3)+8*((r>>2)&3)+32*(r>>4)+4*(lane>>5)]
// (coalesced int4 reads; R8-proven)
// ---------------------------------------------------------------------------
__global__ __launch_bounds__(256)
void conv_maskcol(const int* __restrict__ m, unsigned* __restrict__ o)
{
    int gid = blockIdx.x * 256 + threadIdx.x;      // 2048 blocks -> 524288
    int lane = gid & 63;
    int tile = (gid >> 6) & 31;
    int grp  = (gid >> 11) & 63;
    int bb   = gid >> 17;
    int qrow = grp * 32 + (lane & 31);
    int h = lane >> 5;
    const int* base = m + (size_t)bb * S * S + (size_t)qrow * S + tile * 64 + 4 * h;
    unsigned wbits = 0;
#pragma unroll
    for (int a = 0; a < 8; ++a) {
        int4 v = *(const int4*)(base + 8 * (a & 3) + 32 * (a >> 2));
        wbits |= (v.x != 0 ? 1u : 0u) << (4 * a);
        wbits |= (v.y != 0 ? 1u : 0u) << (4 * a + 1);
        wbits |= (v.z != 0 ? 1u : 0u) << (4 * a + 2);
        wbits |= (v.w != 0 ? 1u : 0u) << (4 * a + 3);
    }
    o[gid] = wbits;
}

// ---------------------------------------------------------------------------
// Fused QKV GEMM, 128x128 tile, BK=64, global_load_lds + XOR swizzle.
// C[8192,3072] = x @ [Wq;Wk;Wv]^T. grid (64, 24); block 256 = 4 waves (2x2).
// Epilogue: q scaled by log2e/8 -> [B,H,S,64]; k -> [B,H,S,64]; v -> [B,H,64,S].
// ---------------------------------------------------------------------------
__global__ __launch_bounds__(256, 3)
void qkv_mfma(const short* __restrict__ xb, const short* __restrict__ wcat,
              const float* __restrict__ bq, const float* __restrict__ bk,
              const float* __restrict__ bv,
              short* __restrict__ qo, short* __restrict__ ko, short* __restrict__ vto)
{
    __shared__ short As[128 * 64];
    __shared__ short Bs[128 * 64];
    const int t = threadIdx.x, lane = t & 63;
    const int w = __builtin_amdgcn_readfirstlane(t >> 6);
    const int lr = lane & 15, lg = lane >> 4;
    const int wr = w >> 1, wc = w & 1;
    const int m0 = blockIdx.x * 128, n0 = blockIdx.y * 128;

    const int srow = t >> 3;                            // 0..31
    const int scol = ((t & 7) ^ (srow & 7)) * 8;        // pre-swizzled col group
    const short* asrc = xb   + (size_t)(m0 + srow) * 1024 + scol;
    const short* bsrc = wcat + (size_t)(n0 + srow) * 1024 + scol;
    char* aldst = (char*)As + w * 1024;                 // HW adds lane*16
    char* bldst = (char*)Bs + w * 1024;

    f32x4 z = {0.f, 0.f, 0.f, 0.f};
    f32x4 acc[4][4];
#pragma unroll
    for (int i = 0; i < 4; ++i)
#pragma unroll
        for (int jj = 0; jj < 4; ++jj) acc[i][jj] = z;

    for (int kt = 0; kt < 1024; kt += 64) {
        __syncthreads();
        GLDS16(asrc + kt,             aldst);
        GLDS16(asrc + kt + 32 * 1024, aldst + 4096);
        GLDS16(asrc + kt + 64 * 1024, aldst + 8192);
        GLDS16(asrc + kt + 96 * 1024, aldst + 12288);
        GLDS16(bsrc + kt,             bldst);
        GLDS16(bsrc + kt + 32 * 1024, bldst + 4096);
        GLDS16(bsrc + kt + 64 * 1024, bldst + 8192);
        GLDS16(bsrc + kt + 96 * 1024, bldst + 12288);
        __syncthreads();
#pragma unroll
        for (int ks = 0; ks < 2; ++ks) {
            bf16x8 af[4], bfr[4];
#pragma unroll
            for (int fi = 0; fi < 4; ++fi) {
                const int ra = wr * 64 + fi * 16 + lr;
                af[fi] = *(const bf16x8*)((const char*)As + ra * 128 +
                          ((ks * 64 + lg * 16) ^ ((ra & 7) << 4)));
                const int rb = wc * 64 + fi * 16 + lr;
                bfr[fi] = *(const bf16x8*)((const char*)Bs + rb * 128 +
                          ((ks * 64 + lg * 16) ^ ((rb & 7) << 4)));
            }
#pragma unroll
            for (int fi = 0; fi < 4; ++fi)
#pragma unroll
                for (int fj = 0; fj < 4; ++fj)
                    acc[fi][fj] = MFMA16(af[fi], bfr[fj], acc[fi][fj]);
        }
    }

    const int bb = m0 >> 11;
    const int ssb = (m0 & (S - 1)) + wr * 64 + lg * 4;
    const int mat = n0 >> 10;
    const int nbase = (n0 & 1023) + wc * 64;

    if (mat == 0) {
#pragma unroll
        for (int fj = 0; fj < 4; ++fj) {
            const int nl = nbase + fj * 16 + lr, hh = nl >> 6, hd = nl & 63;
            const float bi = bq[nl];
#pragma unroll
            for (int fi = 0; fi < 4; ++fi)
#pragma unroll
                for (int r = 0; r < 4; ++r)
                    qo[(((size_t)bb * H + hh) * S + ssb + fi * 16 + r) * 64 + hd] =
                        f2bf((acc[fi][fj][r] + bi) * QSCL);
        }
    } else if (mat == 1) {
#pragma unroll
        for (int fj = 0; fj < 4; ++fj) {
            const int nl = nbase + fj * 16 + lr, hh = nl >> 6, hd = nl & 63;
            const float bi = bk[nl];
#pragma unroll
            for (int fi = 0; fi < 4; ++fi)
#pragma unroll
                for (int r = 0; r < 4; ++r)
                    ko[(((size_t)bb * H + hh) * S + ssb + fi * 16 + r) * 64 + hd] =
                        f2bf(acc[fi][fj][r] + bi);
        }
    } else {
#pragma unroll
        for (int fj = 0; fj < 4; ++fj) {
            const int nl = nbase + fj * 16 + lr, hh = nl >> 6, hd = nl & 63;
            const float bi = bv[nl];
#pragma unroll
            for (int fi = 0; fi < 4; ++fi) {
                s16x4 pk;
#pragma unroll
                for (int r = 0; r < 4; ++r) pk[r] = f2bf(acc[fi][fj][r] + bi);
                *(s16x4*)(vto + (((size_t)bb * H + hh) * 64 + hd) * S + ssb + fi * 16) = pk;
            }
        }
    }
}

// ---------------------------------------------------------------------------
// Flash attention v8: swapped-QK 32x32 MFMA, pure QK+PV matrix work (16
// MFMA32/tile). Mask via per-element select from prefetched column word
// (R8-proven formula) + native exp2. Row-sum li on the VALU (lane owns its
// 32 p-values; cross-half shfl_xor(32)); epilogue 1/li broadcast via
// readlane(qp)/readlane(qp+4) (R3-proven pattern).
// 4 waves x 32 q = 128 q. grid 1024 (XCD-grouped).
// ---------------------------------------------------------------------------
__global__ __launch_bounds__(256, 3)
void attn_mfma8(const short* __restrict__ qg, const short* __restrict__ kg,
                const short* __restrict__ vtg,
                const unsigned* __restrict__ mcol,
                short* __restrict__ hc)
{
    __shared__ short Kl[2][64 * 64];
    __shared__ short Vl[2][64 * 64];

    const int t = threadIdx.x, lane = t & 63;
    const int w = __builtin_amdgcn_readfirstlane(t >> 6);
    const int l31 = lane & 31, h = lane >> 5;

    const int id = blockIdx.x;
    const int xcd = id & 7, j = id >> 3;
    const int bh = xcd + 8 * (j >> 4);
    const int q0 = (j & 15) * 128;
    const int bb = bh >> 4, hh = bh & 15;

    const short* qb  = qg  + (size_t)bh * S * 64;
    const short* kb  = kg  + (size_t)bh * S * 64;
    const short* vtb = vtg + (size_t)bh * 64 * S;
    const unsigned* mc = mcol + ((size_t)(bb * 64 + (q0 >> 5) + w)) * 32 * 64 + lane;

    const int qrow = q0 + w * 32 + l31;
    bf16x8 qf[4];
#pragma unroll
    for (int ds = 0; ds < 4; ++ds)
        qf[ds] = *(const bf16x8*)(qb + (size_t)qrow * 64 + ds * 16 + 8 * h);

    const int sk = t >> 3;                                    // staging row 0..31
    const int soff = (((t & 7) * 16) ^ ((sk & 7) << 4)) >> 1; // pre-swizzled src elem
    const int rbyte = l31 * 128;
    const int sz = (lane & 7) << 4;

    f32x16 z16;
#pragma unroll
    for (int i = 0; i < 16; ++i) z16[i] = 0.f;
    f32x16 O0 = z16, O1 = z16;
    float li = 0.f;

    auto issue_stage = [&](int kt, int buf) {
        const short* ks0 = kb + (size_t)(kt + sk) * 64 + soff;
        const short* vs0 = vtb + (size_t)sk * S + kt + soff;
        char* kB = (char*)&Kl[buf][0] + w * 1024;
        char* vB = (char*)&Vl[buf][0] + w * 1024;
        GLDS16(ks0, kB);
        GLDS16(ks0 + 32 * 64, kB + 4096);
        GLDS16(vs0, vB);
        GLDS16(vs0 + (size_t)32 * S, vB + 4096);
    };

    unsigned mcw = mc[0];
    issue_stage(0, 0);
    __syncthreads();

    for (int tile = 0; tile < 32; ++tile) {
        const int cur = tile & 1;
        unsigned mcn = 0;
        if (tile < 31) {
            issue_stage((tile + 1) * 64, cur ^ 1);
            mcn = mc[(tile + 1) * 64];
        }

        // ---- QK^T (swapped): lane owns q-row l31; acc starts at 0
        f32x16 s0 = z16, s1 = z16;
        const char* Kb = (const char*)&Kl[cur][0];
#pragma unroll
        for (int ds = 0; ds < 4; ++ds) {
            const int off = ((ds * 32 + h * 16) ^ sz);
            bf16x8 a0 = *(const bf16x8*)(Kb + rbyte + off);
            bf16x8 a1 = *(const bf16x8*)(Kb + 4096 + rbyte + off);
            s0 = MFMA32(a0, qf[ds], s0);
            s1 = MFMA32(a1, qf[ds], s1);
        }

        // ---- p = 2^(mask ? s : -inf) ; li += p ; pack ; PV
        const char* Vb = (const char*)&Vl[cur][0];
#pragma unroll
        for (int ks = 0; ks < 4; ++ks) {
            const int rb = (ks < 2) ? ks * 8 : (ks - 2) * 8;
            const int wb = (ks < 2) ? rb : 16 + rb;
            float pv[8];
#pragma unroll
            for (int jj = 0; jj < 8; ++jj) {
                float sv = (ks < 2) ? s0[rb + jj] : s1[rb + jj];
                sv = (mcw & (1u << (wb + jj))) ? sv : -INFINITY;
                pv[jj] = EXP2(sv);
                li += pv[jj];
            }
            int w0a, w1a, w0b, w1b;
            asm volatile("v_cvt_pk_bf16_f32 %0, %1, %2" : "=v"(w0a) : "v"(pv[0]), "v"(pv[1]));
            asm volatile("v_cvt_pk_bf16_f32 %0, %1, %2" : "=v"(w1a) : "v"(pv[2]), "v"(pv[3]));
            asm volatile("v_cvt_pk_bf16_f32 %0, %1, %2" : "=v"(w0b) : "v"(pv[4]), "v"(pv[5]));
            asm volatile("v_cvt_pk_bf16_f32 %0, %1, %2" : "=v"(w1b) : "v"(pv[6]), "v"(pv[7]));
            asm volatile("v_permlane32_swap_b32 %0, %1" : "+v"(w0a), "+v"(w0b));
            asm volatile("v_permlane32_swap_b32 %0, %1" : "+v"(w1a), "+v"(w1b));
            union { int i[4]; bf16x8 v; } pf;
            pf.i[0] = w0a; pf.i[1] = w1a; pf.i[2] = w0b; pf.i[3] = w1b;

            const int koff = ((ks * 32 + h * 16) ^ sz);
            bf16x8 v0 = *(const bf16x8*)(Vb + rbyte + koff);
            bf16x8 v1 = *(const bf16x8*)(Vb + 4096 + rbyte + koff);
            O0 = MFMA32(pf.v, v0, O0);
            O1 = MFMA32(pf.v, v1, O1);
        }

        if (tile < 31) mcw = mcn;
        __syncthreads();
    }

    // ---- epilogue: combine half-row sums, broadcast 1/li to output regs
    li += __shfl_xor(li, 32);             // full row-sum for q-row l31
    const float inv = 1.f / li;
    const int ib = __builtin_bit_cast(int, inv);
    const size_t outb = (size_t)bb * S * D + (size_t)hh * 64;
#pragma unroll
    for (int r = 0; r < 16; ++r) {
        const int qp = (r & 3) + 8 * (r >> 2);
        const int vlo = __builtin_amdgcn_readlane(ib, qp);
        const int vhi = __builtin_amdgcn_readlane(ib, qp + 4);
        const float ir = h ? __builtin_bit_cast(float, vhi)
                           : __builtin_bit_cast(float, vlo);
        const int row = q0 + w * 32 + qp + 4 * h;
        hc[outb + (size_t)row * D + l31]      = f2bf(O0[r] * ir);
        hc[outb + (size_t)row * D + 32 + l31] = f2bf(O1[r] * ir);
    }
}

// ---------------------------------------------------------------------------
// Output projection, 128x128 tile, fp32 out. grid (64, 8); block 256.
// ---------------------------------------------------------------------------
__global__ __launch_bounds__(256, 3)
void proj_mfma(const short* __restrict__ hb, const short* __restrict__ wfb,
               const float* __restrict__ bfp, float* __restrict__ out)
{
    __shared__ short As[128 * 64];
    __shared__ short Bs[128 * 64];
    const int t = threadIdx.x, lane = t & 63;
    const int w = __builtin_amdgcn_readfirstlane(t >> 6);
    const int lr = lane & 15, lg = lane >> 4;
    const int wr = w >> 1, wc = w & 1;
    const int m0 = blockIdx.x * 128, n0 = blockIdx.y * 128;

    const int srow = t >> 3;
    const int scol = ((t & 7) ^ (srow & 7)) * 8;
    const short* asrc = hb  + (size_t)(m0 + srow) * 1024 + scol;
    const short* bsrc = wfb + (size_t)(n0 + srow) * 1024 + scol;
    char* aldst = (char*)As + w * 1024;
    char* bldst = (char*)Bs + w * 1024;

    f32x4 z = {0.f, 0.f, 0.f, 0.f};
    f32x4 acc[4][4];
#pragma unroll
    for (int i = 0; i < 4; ++i)
#pragma unroll
        for (int jj = 0; jj < 4; ++jj) acc[i][jj] = z;

    for (int kt = 0; kt < 1024; kt += 64) {
        __syncthreads();
        GLDS16(asrc + kt,             aldst);
        GLDS16(asrc + kt + 32 * 1024, aldst + 4096);
        GLDS16(asrc + kt + 64 * 1024, aldst + 8192);
        GLDS16(asrc + kt + 96 * 1024, aldst + 12288);
        GLDS16(bsrc + kt,             bldst);
        GLDS16(bsrc + kt + 32 * 1024, bldst + 4096);
        GLDS16(bsrc + kt + 64 * 1024, bldst + 8192);
        GLDS16(bsrc + kt + 96 * 1024, bldst + 12288);
        __syncthreads();
#pragma unroll
        for (int ks = 0; ks < 2; ++ks) {
            bf16x8 af[4], bfr[4];
#pragma unroll
            for (int fi = 0; fi < 4; ++fi) {
                const int ra = wr * 64 + fi * 16 + lr;
                af[fi] = *(const bf16x8*)((const char*)As + ra * 128 +
                          ((ks * 64 + lg * 16) ^ ((ra & 7) << 4)));
                const int rb = wc * 64 + fi * 16 + lr;
                bfr[fi] = *(const bf16x8*)((const char*)Bs + rb * 128 +
                          ((ks * 64 + lg * 16) ^ ((rb & 7) << 4)));
            }
#pragma unroll
            for (int fi = 0; fi < 4; ++fi)
#pragma unroll
                for (int fj = 0; fj < 4; ++fj)
                    acc[fi][fj] = MFMA16(af[fi], bfr[fj], acc[fi][fj]);
        }
    }

#pragma unroll
    for (int fj = 0; fj < 4; ++fj) {
        const int nl = n0 + wc * 64 + fj * 16 + lr;
        const float bi = bfp[nl];
#pragma unroll
        for (int fi = 0; fi < 4; ++fi)
#pragma unroll
            for (int r = 0; r < 4; ++r)
                out[(size_t)(m0 + wr * 64 + fi * 16 + lg * 4 + r) * 1024 + nl] =
                    acc[fi][fj][r] + bi;
    }
}

// ---------------------------------------------------------------------------
extern "C" void kernel_launch(void* const* d_in, const int* in_sizes, int n_in,
                              void* d_out, int out_size, void* d_ws, size_t ws_size,
                              hipStream_t stream)
{
    const float* x  = (const float*)d_in[0];
    const int* mask = (const int*)d_in[1];
    const float* Wq = (const float*)d_in[2];
    const float* bq = (const float*)d_in[3];
    const float* Wk = (const float*)d_in[4];
    const float* bk = (const float*)d_in[5];
    const float* Wv = (const float*)d_in[6];
    const float* bv = (const float*)d_in[7];
    const float* Wf = (const float*)d_in[8];
    const float* bf = (const float*)d_in[9];
    float* out = (float*)d_out;

    char* p = (char*)d_ws;
    short* xb  = (short*)p; p += 16777216;                       // x bf16
    short* wqb = (short*)p; p += 2097152;                        // [Wq;Wk;Wv;Wf] bf16
    short* wkb = (short*)p; p += 2097152;
    short* wvb = (short*)p; p += 2097152;
    short* wfb = (short*)p; p += 2097152;
    short* qb  = (short*)p; p += 16777216;                       // [B,H,S,64]
    short* kb  = (short*)p; p += 16777216;                       // [B,H,S,64]
    short* vtb = (short*)p; p += 16777216;                       // [B,H,64,S]
    short* hcb = (short*)p; p += 16777216;                       // [B,S,D]
    unsigned* mcol = (unsigned*)p; p += 2097152;                 // mask column words

    conv_pack<<<12288, 256, 0, stream>>>(x, Wq, Wk, Wv, Wf, xb, wqb, wkb, wvb, wfb);
    conv_maskcol<<<2048, 256, 0, stream>>>(mask, mcol);
    qkv_mfma<<<dim3(64, 24), 256, 0, stream>>>(xb, wqb, bq, bk, bv, qb, kb, vtb);
    attn_mfma8<<<1024, 256, 0, stream>>>(qb, kb, vtb, mcol, hcb);
    proj_mfma<<<dim3(64, 8), 256, 0, stream>>>(hcb, wfb, bf, out);
}